// Round 7
// baseline (195.363 us; speedup 1.0000x reference)
//
#include <hip/hip_runtime.h>

#define NPIX 409600   // 640*640
#define NB 8          // batch

// ---------------- workspace layout (4-byte words, per batch) ----------------
constexpr int OFF_H0   = 0;     // 2048 u32  level-0 histogram (key bits 31..21)
constexpr int OFF_KC   = 2048;  // 8 u32   kernel-mask counts (idx 1..7 used)
constexpr int OFF_TC   = 2056;  // 8 u32   text-mask counts
constexpr int OFF_KS   = 2064;  // 32 f32  kernel-mask sim sums (inst*4+c, inst 1..7)
constexpr int OFF_AGG  = 2096;  // 8 f32   per-instance sum log1p(D)
constexpr int OFF_CPOS = 2104;  // u32
constexpr int OFF_CPOSM= 2105;  // u32  pos & tm<=0.5
constexpr int OFF_KN   = 2106;  // u32  compact neg-key count
constexpr int OFF_KNF  = 2107;  // u32  flagged (mv>0.5) neg-key count
constexpr int OFF_FALL = 2108;  // u32
constexpr int OFF_NV   = 2109;  // u32
constexpr int OFF_VM   = 2110;  // u32
constexpr int OFF_LDIS = 2111;  // f32
constexpr int OFF_BTN  = 2112;  // f32  bt_neg (threshold-dependent dice part)
constexpr int OFF_DICE = 2113;  // 9 f32: at,btp,ct, atf,btf,ctf, ak,bk,ck
constexpr int PER_BATCH= 2176;
constexpr int KEYS_BASE= NB * PER_BATCH;   // 17408 words
constexpr int HDR_WORDS= NB * PER_BATCH;   // 69.6 KB to zero
// per-batch key region (NPIX words): list A (all negs) grows up from 0,
// list B (flagged negs) grows down from NPIX-1. |A|+|B| ~ 77K << NPIX.

__device__ __forceinline__ unsigned mapf(float s) {
  unsigned b = __float_as_uint(s);
  return (b & 0x80000000u) ? ~b : (b | 0x80000000u);
}
__device__ __forceinline__ float unmapf(unsigned u) {
  return __uint_as_float((u & 0x80000000u) ? (u & 0x7FFFFFFFu) : ~u);
}
__device__ __forceinline__ float wredf(float v) {
#pragma unroll
  for (int m = 32; m >= 1; m >>= 1) v += __shfl_xor(v, m, 64);
  return v;
}
__device__ __forceinline__ unsigned wredu(unsigned v) {
#pragma unroll
  for (int m = 32; m >= 1; m >>= 1) v += (unsigned)__shfl_xor((int)v, m, 64);
  return v;
}

// ---- kZ: zero workspace header (69.6 KB) -----------------------------------
__global__ __launch_bounds__(256) void kZ(unsigned* __restrict__ ws) {
  int i = blockIdx.x * 256 + threadIdx.x;
  if (i < HDR_WORDS) ws[i] = 0u;
}

// ---- kXS: single launch, two roles ------------------------------------------
// role X (blocks 0..199): tx,kr,gt,gk,tm -> hist0, cpos/cposm, TC, pos-dice,
//   fallback-dice, kernel-dice, key compaction (A + flagged B).
// role S (blocks 200..399): gk,sim -> KS sums + KC counts via fire-and-forget
//   per-lane-slot ds_add_f32 (no RMW chain, no cross-lane collisions).
__global__ __launch_bounds__(256) void kXS(const float* __restrict__ out_,
                                           const int* __restrict__ lab_,
                                           const float* __restrict__ tm_,
                                           unsigned* __restrict__ ws) {
  const int b = blockIdx.y;
  unsigned* wsb = ws + (size_t)b * PER_BATCH;
  float* wsbf = (float*)wsb;
  __shared__ unsigned shA[2048];   // X: hist0 | S: f32 [c][inst][lane] sums
  __shared__ unsigned shB[512];    // X: TC [inst][lane] | S: KC [inst][lane]
  __shared__ unsigned shScan[256];
  __shared__ float shRed[4 * 9];
  __shared__ unsigned shC[4 * 2];
  __shared__ unsigned shBase[2];
  const int tid = threadIdx.x, lane = tid & 63, w = tid >> 6;
  const bool roleX = blockIdx.x < 200;
  const int bx = roleX ? blockIdx.x : (blockIdx.x - 200);
  for (int i = tid; i < 2048; i += 256) shA[i] = 0u;
  for (int i = tid; i < 512; i += 256) shB[i] = 0u;
  __syncthreads();

  if (roleX) {
    const float4* tx = (const float4*)(out_ + (size_t)b * 6 * NPIX);
    const float4* kr = (const float4*)(out_ + (size_t)b * 6 * NPIX + (size_t)NPIX);
    const int4* gt = (const int4*)(lab_ + (size_t)b * 2 * NPIX);
    const int4* gk = (const int4*)(lab_ + (size_t)b * 2 * NPIX + NPIX);
    const float4* tmv = (const float4*)(tm_ + (size_t)b * NPIX);

    unsigned cpos = 0, cposm = 0, vmask = 0, fmask = 0;
    unsigned kreg[8];
    float at = 0.f, btp = 0.f, ct = 0.f, atf = 0.f, btf = 0.f, ctf = 0.f;
    float ak = 0.f, bk = 0.f, ck = 0.f;
#pragma unroll
    for (int it = 0; it < 2; ++it) {
      const int i = it * 51200 + bx * 256 + tid;
      float4 t4 = tx[i]; float4 q4 = kr[i]; int4 g4 = gt[i]; int4 k4 = gk[i]; float4 m4 = tmv[i];
#pragma unroll
      for (int j = 0; j < 4; ++j) {
        float tv = ((const float*)&t4)[j];
        float kv = ((const float*)&q4)[j];
        int gtv = ((const int*)&g4)[j];
        int gkv = ((const int*)&k4)[j];
        float mv = ((const float*)&m4)[j];
        bool pos = gtv > 0;
        bool mh = mv > 0.5f;
        cpos += pos;
        cposm += (pos && !mh);
        unsigned key = mapf(tv);
        kreg[it * 4 + j] = key;
        float sig = 1.f / (1.f + expf(-tv));
        if (!pos) {
          vmask |= 1u << (it * 4 + j);
          fmask |= (mh ? 1u : 0u) << (it * 4 + j);
          atomicAdd(&shA[key >> 21], 1u);
        } else {
          atomicAdd(&shB[(gtv - 1) * 64 + lane], 1u);
          if (mh) { at += sig; btp += sig * sig; ct += 1.f; }
        }
        float sm = sig * mv;          // fallback (sel = tm float)
        btf += sm * sm;
        if (pos) { atf += sm * mv; ctf += mv * mv; }
        if ((tv > 0.f) && mh) {       // kernel dice: selk
          float sk = 1.f / (1.f + expf(-kv));
          bk += sk * sk;
          if (gkv > 0) { ak += sk; ck += 1.f; }
        }
      }
    }
    unsigned r = wredu(cpos), r2 = wredu(cposm);
    if (lane == 0) { shC[w * 2] = r; shC[w * 2 + 1] = r2; }
    float v9[9] = {at, btp, ct, atf, btf, ctf, ak, bk, ck};
#pragma unroll
    for (int q = 0; q < 9; ++q) {
      float f = wredf(v9[q]);
      if (lane == 0) shRed[w * 9 + q] = f;
    }
    unsigned cnt = (unsigned)__popc(vmask), cntF = (unsigned)__popc(fmask);
    shScan[tid] = cnt | (cntF << 16);
    __syncthreads();
#pragma unroll
    for (int off = 1; off < 256; off <<= 1) {
      unsigned vv = (tid >= off) ? shScan[tid - off] : 0u;
      __syncthreads();
      shScan[tid] += vv;
      __syncthreads();
    }
    if (tid == 0) {
      unsigned tot = shScan[255];
      shBase[0] = atomicAdd(&wsb[OFF_KN], tot & 0xFFFFu);
      shBase[1] = atomicAdd(&wsb[OFF_KNF], tot >> 16);
    }
    for (int i = tid; i < 2048; i += 256) {
      unsigned h = shA[i]; if (h) atomicAdd(&wsb[OFF_H0 + i], h);
    }
    if (tid < 7) {
      unsigned s = 0;
#pragma unroll
      for (int l = 0; l < 64; ++l) s += shB[tid * 64 + l];
      if (s) atomicAdd(&wsb[OFF_TC + 1 + tid], s);
    } else if (tid >= 16 && tid < 25) {
      int q = tid - 16;
      float s = shRed[q] + shRed[9 + q] + shRed[18 + q] + shRed[27 + q];
      atomicAdd(&wsbf[OFF_DICE + q], s);
    } else if (tid == 30) {
      atomicAdd(&wsb[OFF_CPOS], shC[0] + shC[2] + shC[4] + shC[6]);
    } else if (tid == 31) {
      atomicAdd(&wsb[OFF_CPOSM], shC[1] + shC[3] + shC[5] + shC[7]);
    }
    __syncthreads();   // shBase ready
    unsigned myA = (shScan[tid] & 0xFFFFu) - cnt;
    unsigned myF = (shScan[tid] >> 16) - cntF;
    unsigned* keys = ws + KEYS_BASE + (size_t)b * NPIX;
    unsigned gA = shBase[0] + myA, gF = shBase[1] + myF;
#pragma unroll
    for (int s = 0; s < 8; ++s)
      if (vmask & (1u << s)) { keys[gA] = kreg[s]; ++gA; }
#pragma unroll
    for (int s = 0; s < 8; ++s)
      if (fmask & (1u << s)) { keys[NPIX - 1 - gF] = kreg[s]; ++gF; }
  } else {
    // ---- role S ----
    const float4* s0 = (const float4*)(out_ + (size_t)b * 6 * NPIX + 2 * (size_t)NPIX);
    const float4* s1 = (const float4*)(out_ + (size_t)b * 6 * NPIX + 3 * (size_t)NPIX);
    const float4* s2 = (const float4*)(out_ + (size_t)b * 6 * NPIX + 4 * (size_t)NPIX);
    const float4* s3 = (const float4*)(out_ + (size_t)b * 6 * NPIX + 5 * (size_t)NPIX);
    const int4* gkk = (const int4*)(lab_ + (size_t)b * 2 * NPIX + NPIX);
    float* Lf = (float*)shA;   // [c 0..3][inst 0..7][lane 0..63]
#pragma unroll
    for (int it = 0; it < 2; ++it) {
      const int i = it * 51200 + bx * 256 + tid;
      int4 k4 = gkk[i];
      float4 a0 = s0[i], a1 = s1[i], a2 = s2[i], a3 = s3[i];
#pragma unroll
      for (int j = 0; j < 4; ++j) {
        int gkv = ((const int*)&k4)[j];
        if (gkv > 0) {
          int idx = gkv - 1;
          atomicAdd(&Lf[0 * 512 + idx * 64 + lane], ((const float*)&a0)[j]);
          atomicAdd(&Lf[1 * 512 + idx * 64 + lane], ((const float*)&a1)[j]);
          atomicAdd(&Lf[2 * 512 + idx * 64 + lane], ((const float*)&a2)[j]);
          atomicAdd(&Lf[3 * 512 + idx * 64 + lane], ((const float*)&a3)[j]);
          atomicAdd(&shB[idx * 64 + lane], 1u);
        }
      }
    }
    __syncthreads();
    if (tid < 28) {
      int idx = tid % 7, c = tid / 7;
      float s = 0.f;
#pragma unroll
      for (int l = 0; l < 64; ++l) s += Lf[c * 512 + idx * 64 + l];
      if (s != 0.f) atomicAdd(&wsbf[OFF_KS + (idx + 1) * 4 + c], s);
    } else if (tid >= 32 && tid < 39) {
      int idx = tid - 32;
      unsigned s = 0;
#pragma unroll
      for (int l = 0; l < 64; ++l) s += shB[idx * 64 + l];
      if (s) atomicAdd(&wsb[OFF_KC + 1 + idx], s);
    }
  }
}

// ---- kGS: agg-role blocks (1..100) + one select-role block (0) per batch ----
__global__ __launch_bounds__(256) void kGS(const float* __restrict__ out_,
                                           const int* __restrict__ lab_,
                                           unsigned* __restrict__ ws) {
  const int b = blockIdx.y;
  unsigned* wsb = ws + (size_t)b * PER_BATCH;
  float* wsbf = (float*)wsb;
  __shared__ unsigned U[2048];
  __shared__ unsigned S2[256];
  __shared__ float sG[32];
  __shared__ unsigned sh_k, sh_pfx0, sh_pfx22, sh_thk;
  __shared__ int sh_fall;
  const int tid = threadIdx.x, lane = tid & 63, w = tid >> 6;

  if (blockIdx.x != 0) {
    // ================= agg role =================
    const int bx = blockIdx.x - 1;
    float* LA = (float*)U;   // [inst 0..6][lane 0..63]
    for (int i = tid; i < 512; i += 256) LA[i] = 0.f;
    if (tid < 32) {
      int inst = tid >> 2, c = tid & 3;
      float g = 0.f;
      if (inst >= 1) {
        unsigned kc = wsb[OFF_KC + inst];
        g = wsbf[OFF_KS + inst * 4 + c] / fmaxf((float)kc, 1.f);
      }
      sG[tid] = g;
    }
    __syncthreads();
    const int4* gt = (const int4*)(lab_ + (size_t)b * 2 * NPIX);
    const float4* s0 = (const float4*)(out_ + (size_t)b * 6 * NPIX + 2 * (size_t)NPIX);
    const float4* s1 = (const float4*)(out_ + (size_t)b * 6 * NPIX + 3 * (size_t)NPIX);
    const float4* s2 = (const float4*)(out_ + (size_t)b * 6 * NPIX + 4 * (size_t)NPIX);
    const float4* s3 = (const float4*)(out_ + (size_t)b * 6 * NPIX + 5 * (size_t)NPIX);
#pragma unroll
    for (int it = 0; it < 4; ++it) {
      const int i = it * 25600 + bx * 256 + tid;
      int4 g4 = gt[i];
      float4 a0 = s0[i], a1 = s1[i], a2 = s2[i], a3 = s3[i];
#pragma unroll
      for (int j = 0; j < 4; ++j) {
        int gtv = ((const int*)&g4)[j];
        if (gtv > 0) {
          float d0 = ((const float*)&a0)[j] - sG[gtv * 4 + 0];
          float d1 = ((const float*)&a1)[j] - sG[gtv * 4 + 1];
          float d2 = ((const float*)&a2)[j] - sG[gtv * 4 + 2];
          float d3 = ((const float*)&a3)[j] - sG[gtv * 4 + 3];
          float sq = d0 * d0 + d1 * d1 + d2 * d2 + d3 * d3;
          float d = (sq > 0.f) ? sqrtf(sq) : 0.f;
          float dd = fmaxf(d - 0.5f, 0.f);
          atomicAdd(&LA[(gtv - 1) * 64 + lane], log1pf(dd * dd));
        }
      }
    }
    __syncthreads();
    if (tid < 7) {
      float s = 0.f;
#pragma unroll
      for (int l = 0; l < 64; ++l) s += LA[tid * 64 + l];
      if (s != 0.f) atomicAdd(&wsbf[OFF_AGG + 1 + tid], s);
    }
    return;
  }

  // ================= select role =================
  if (tid == 0) {
    unsigned cpos = wsb[OFF_CPOS], cposm = wsb[OFF_CPOSM];
    long posnum = (long)cpos - (long)cposm;
    long cneg = (long)NPIX - (long)cpos;
    long negnum = posnum * 3; if (negnum > cneg) negnum = cneg;
    int fall = (posnum == 0) || (negnum == 0);
    wsb[OFF_FALL] = (unsigned)fall;
    sh_fall = fall; sh_k = (unsigned)negnum;
    float G[8][4];
    unsigned nvv = 0, vm = 0;
    for (int k = 1; k < 8; ++k) {
      unsigned kc = wsb[OFF_KC + k], tc = wsb[OFF_TC + k];
      float inv = 1.f / fmaxf((float)kc, 1.f);
      for (int c = 0; c < 4; ++c) G[k][c] = wsbf[OFF_KS + k * 4 + c] * inv;
      if (kc > 0 && tc > 0) { vm |= 1u << k; ++nvv; }
    }
    wsb[OFF_NV] = nvv; wsb[OFF_VM] = vm;
    float s = 0.f;
    for (int i = 1; i < 8; ++i) {
      if (!((vm >> i) & 1)) continue;
      for (int j = i + 1; j < 8; ++j) {
        if (!((vm >> j) & 1)) continue;
        float sq = 0.f;
        for (int c = 0; c < 4; ++c) { float d = G[i][c] - G[j][c]; sq += d * d; }
        float gn = (sq > 0.f) ? sqrtf(sq) : 0.f;
        float dd = fmaxf(3.0f - gn, 0.f);
        s += log1pf(dd * dd);
      }
    }
    float denom = (float)(nvv * (nvv > 0 ? nvv - 1u : 0u));
    wsbf[OFF_LDIS] = (nvv > 1) ? (s / fmaxf(denom, 1.f)) : 0.f;
    if (fall) wsbf[OFF_BTN] = 0.f;
  }
  __syncthreads();
  if (sh_fall) return;
  const unsigned kn = wsb[OFF_KN], knF = wsb[OFF_KNF];
  const unsigned* keys = ws + KEYS_BASE + (size_t)b * NPIX;

  // ---- level 0 from global H0 ----
  unsigned myp = 0;
#pragma unroll
  for (int j = 0; j < 8; ++j) myp += wsb[OFF_H0 + tid * 8 + j];
  S2[tid] = myp;
  __syncthreads();
#pragma unroll
  for (int off = 1; off < 256; off <<= 1) {
    unsigned v = (tid + off < 256) ? S2[tid + off] : 0u;
    __syncthreads();
    S2[tid] += v;
    __syncthreads();
  }
  {
    unsigned k = sh_k;
    unsigned suf = S2[tid], sufn = suf - myp;
    __syncthreads();
    if (suf >= k && sufn < k) {
      unsigned kk = k - sufn;
      unsigned cum2 = 0; int bin = tid * 8;
#pragma unroll
      for (int j = 7; j >= 0; --j) {
        unsigned h = wsb[OFF_H0 + tid * 8 + j]; cum2 += h;
        if (cum2 >= kk) { bin = tid * 8 + j; kk -= (cum2 - h); break; }
      }
      sh_pfx0 = (unsigned)bin; sh_k = kk;
    }
  }
  __syncthreads();
  const unsigned pfx0 = sh_pfx0;

  // ---- level 1: histogram bits 20..10 from key list A ----
  for (int i = tid; i < 2048; i += 256) U[i] = 0u;
  __syncthreads();
  for (unsigned q = tid; q * 4 < kn; q += 256) {
    uint4 k4 = ((const uint4*)keys)[q];
#pragma unroll
    for (int e = 0; e < 4; ++e) {
      unsigned idx = q * 4 + e;
      if (idx < kn) {
        unsigned key = ((const unsigned*)&k4)[e];
        if ((key >> 21) == pfx0) atomicAdd(&U[(key >> 10) & 0x7FFu], 1u);
      }
    }
  }
  __syncthreads();
  myp = 0;
#pragma unroll
  for (int j = 0; j < 8; ++j) myp += U[tid * 8 + j];
  S2[tid] = myp;
  __syncthreads();
#pragma unroll
  for (int off = 1; off < 256; off <<= 1) {
    unsigned v = (tid + off < 256) ? S2[tid + off] : 0u;
    __syncthreads();
    S2[tid] += v;
    __syncthreads();
  }
  {
    unsigned k = sh_k;
    unsigned suf = S2[tid], sufn = suf - myp;
    __syncthreads();
    if (suf >= k && sufn < k) {
      unsigned kk = k - sufn;
      unsigned cum2 = 0; int bin = tid * 8;
#pragma unroll
      for (int j = 7; j >= 0; --j) {
        unsigned h = U[tid * 8 + j]; cum2 += h;
        if (cum2 >= kk) { bin = tid * 8 + j; kk -= (cum2 - h); break; }
      }
      sh_pfx22 = (pfx0 << 11) | (unsigned)bin; sh_k = kk;
    }
  }
  __syncthreads();
  const unsigned pfx22 = sh_pfx22;

  // ---- level 2: bits 9..0 ----
  for (int i = tid; i < 1024; i += 256) U[i] = 0u;
  __syncthreads();
  for (unsigned q = tid; q * 4 < kn; q += 256) {
    uint4 k4 = ((const uint4*)keys)[q];
#pragma unroll
    for (int e = 0; e < 4; ++e) {
      unsigned idx = q * 4 + e;
      if (idx < kn) {
        unsigned key = ((const unsigned*)&k4)[e];
        if ((key >> 10) == pfx22) atomicAdd(&U[key & 0x3FFu], 1u);
      }
    }
  }
  __syncthreads();
  myp = 0;
#pragma unroll
  for (int j = 0; j < 4; ++j) myp += U[tid * 4 + j];
  S2[tid] = myp;
  __syncthreads();
#pragma unroll
  for (int off = 1; off < 256; off <<= 1) {
    unsigned v = (tid + off < 256) ? S2[tid + off] : 0u;
    __syncthreads();
    S2[tid] += v;
    __syncthreads();
  }
  {
    unsigned k = sh_k;
    unsigned suf = S2[tid], sufn = suf - myp;
    __syncthreads();
    if (suf >= k && sufn < k) {
      unsigned kk = k - sufn;
      unsigned cum2 = 0; int bin = tid * 4;
#pragma unroll
      for (int j = 3; j >= 0; --j) {
        unsigned h = U[tid * 4 + j]; cum2 += h;
        if (cum2 >= kk) { bin = tid * 4 + j; break; }
      }
      sh_thk = (pfx22 << 10) | (unsigned)bin;
    }
  }
  __syncthreads();
  const unsigned thkey = sh_thk;

  // ---- bt_neg over flagged list (stored at [NPIX-knF, NPIX-1]) ----
  float part = 0.f;
  for (unsigned i = tid; i < knF; i += 256) {
    unsigned key = keys[NPIX - knF + i];
    if (key >= thkey) {
      float tv = unmapf(key);
      float sg = 1.f / (1.f + expf(-tv));
      part += sg * sg;
    }
  }
  part = wredf(part);
  float* sF = (float*)sG;
  if (lane == 0) sF[w] = part;
  __syncthreads();
  if (tid == 0) wsbf[OFF_BTN] = sF[0] + sF[1] + sF[2] + sF[3];
}

// ---- kH: finalize 5 scalars -------------------------------------------------
__global__ void kH(const unsigned* __restrict__ ws, float* __restrict__ out) {
  __shared__ float sv[4][8];
  const int b = threadIdx.x;
  if (b < 8) {
    const unsigned* wsb = ws + (size_t)b * PER_BATCH;
    const float* wsbf = (const float*)wsb;
    int fall = (int)wsb[OFF_FALL];
    float at, bt, ct;
    if (fall) {
      at = wsbf[OFF_DICE + 3]; bt = wsbf[OFF_DICE + 4]; ct = wsbf[OFF_DICE + 5];
    } else {
      at = wsbf[OFF_DICE + 0];
      bt = wsbf[OFF_DICE + 1] + wsbf[OFF_BTN];
      ct = wsbf[OFF_DICE + 2];
    }
    float lt = 1.f - 2.f * at / ((bt + 1e-3f) + (ct + 1e-3f));
    float ak = wsbf[OFF_DICE + 6], bk = wsbf[OFF_DICE + 7] + 1e-3f, ck = wsbf[OFF_DICE + 8] + 1e-3f;
    float lk = 1.f - 2.f * ak / (bk + ck);
    unsigned vm = wsb[OFF_VM], nvv = wsb[OFF_NV];
    float s = 0.f;
    for (int k = 1; k < 8; ++k)
      if ((vm >> k) & 1) s += wsbf[OFF_AGG + k] / fmaxf((float)wsb[OFF_TC + k], 1.f);
    float la = s / fmaxf((float)nvv, 1.f);
    float ld = wsbf[OFF_LDIS];
    sv[0][b] = lt; sv[1][b] = lk; sv[2][b] = la; sv[3][b] = ld;
  }
  __syncthreads();
  if (threadIdx.x == 0) {
    float mt = 0.f, mk = 0.f, ma = 0.f, md = 0.f;
    for (int i = 0; i < 8; ++i) { mt += sv[0][i]; mk += sv[1][i]; ma += sv[2][i]; md += sv[3][i]; }
    mt *= 0.125f; mk *= 0.125f; ma *= 0.125f; md *= 0.125f;
    out[0] = mt + 0.5f * mk + 0.25f * (ma + md);
    out[1] = mt;
    out[2] = mk;
    out[3] = ma;
    out[4] = md;
  }
}

extern "C" void kernel_launch(void* const* d_in, const int* in_sizes, int n_in,
                              void* d_out, int out_size, void* d_ws, size_t ws_size,
                              hipStream_t stream) {
  const float* outputs = (const float*)d_in[0];
  const int* labels = (const int*)d_in[1];
  const float* tm = (const float*)d_in[2];
  unsigned* ws = (unsigned*)d_ws;
  float* out = (float*)d_out;

  dim3 blk(256);
  kZ<<<(HDR_WORDS + 255) / 256, blk, 0, stream>>>(ws);
  kXS<<<dim3(400, NB), blk, 0, stream>>>(outputs, labels, tm, ws);
  kGS<<<dim3(101, NB), blk, 0, stream>>>(outputs, labels, ws);
  kH<<<1, 64, 0, stream>>>(ws, out);
}

// Round 8
// 146.031 us; speedup vs baseline: 1.3378x; 1.3378x over previous
//
#include <hip/hip_runtime.h>

#define NPIX 409600   // 640*640
#define NB 8          // batch

// ---------------- workspace layout (4-byte words, per batch) ----------------
constexpr int OFF_H0   = 0;     // 2048 u32  level-0 histogram (key bits 31..21)
constexpr int OFF_KC   = 2048;  // 8 u32   kernel-mask counts (idx 1..7 used)
constexpr int OFF_TC   = 2056;  // 8 u32   text-mask counts
constexpr int OFF_KS   = 2064;  // 32 f32  kernel-mask sim sums (inst*4+c)
constexpr int OFF_AGG  = 2096;  // 8 f32   per-instance sum log1p(D)
constexpr int OFF_CPOS = 2104;  // u32
constexpr int OFF_CPOSM= 2105;  // u32  pos & tm<=0.5
constexpr int OFF_KN   = 2106;  // u32  compact neg-key count (list A)
constexpr int OFF_KNF  = 2107;  // u32  flagged neg-key count (list B)
constexpr int OFF_FALL = 2108;  // u32
constexpr int OFF_NV   = 2109;  // u32
constexpr int OFF_VM   = 2110;  // u32
constexpr int OFF_LDIS = 2111;  // f32
constexpr int OFF_BTN  = 2112;  // f32  bt_neg (threshold-dependent dice part)
constexpr int OFF_DICE = 2113;  // 9 f32: at,btp,ct, atf,btf,ctf, ak,bk,ck
constexpr int PER_BATCH= 2176;
constexpr int KEYS_BASE= NB * PER_BATCH;
constexpr int HDR_WORDS= NB * PER_BATCH;   // 68 KB to zero
// per-batch key region (NPIX words): list A (all negs) grows up from 0,
// list B (flagged negs) grows down from NPIX-1.

__device__ __forceinline__ unsigned mapf(float s) {
  unsigned b = __float_as_uint(s);
  return (b & 0x80000000u) ? ~b : (b | 0x80000000u);
}
__device__ __forceinline__ float unmapf(unsigned u) {
  return __uint_as_float((u & 0x80000000u) ? (u & 0x7FFFFFFFu) : ~u);
}
__device__ __forceinline__ float wredf(float v) {
#pragma unroll
  for (int m = 32; m >= 1; m >>= 1) v += __shfl_xor(v, m, 64);
  return v;
}
__device__ __forceinline__ unsigned wredu(unsigned v) {
#pragma unroll
  for (int m = 32; m >= 1; m >>= 1) v += (unsigned)__shfl_xor((int)v, m, 64);
  return v;
}

// ---- kZ: zero workspace header ---------------------------------------------
__global__ __launch_bounds__(256) void kZ(unsigned* __restrict__ ws) {
  int i = blockIdx.x * 256 + threadIdx.x;
  if (i < HDR_WORDS) ws[i] = 0u;
}

// ---- kX: tx,kr,gt,gk,tm -> hist0, cpos/cposm, TC (ballot), all
//      threshold-independent dice sums (9 register accumulators),
//      dual register-resident key compaction (R4-proven mechanics) ----------
__global__ __launch_bounds__(256) void kX(const float* __restrict__ out_,
                                          const int* __restrict__ lab_,
                                          const float* __restrict__ tm_,
                                          unsigned* __restrict__ ws) {
  const int b = blockIdx.y;
  unsigned* wsb = ws + (size_t)b * PER_BATCH;
  float* wsbf = (float*)wsb;
  __shared__ unsigned sh_h[2048];
  __shared__ unsigned shScan[256];
  __shared__ unsigned shTC[4 * 7];
  __shared__ float shRed[4 * 9];
  __shared__ unsigned shC[4 * 2];
  __shared__ unsigned shBase[2];
  const int tid = threadIdx.x, lane = tid & 63, w = tid >> 6;
  for (int i = tid; i < 2048; i += 256) sh_h[i] = 0u;
  __syncthreads();

  const float4* tx = (const float4*)(out_ + (size_t)b * 6 * NPIX);
  const float4* kr = (const float4*)(out_ + (size_t)b * 6 * NPIX + (size_t)NPIX);
  const int4* gt = (const int4*)(lab_ + (size_t)b * 2 * NPIX);
  const int4* gk = (const int4*)(lab_ + (size_t)b * 2 * NPIX + NPIX);
  const float4* tmv = (const float4*)(tm_ + (size_t)b * NPIX);

  unsigned cpos = 0, cposm = 0, vmask = 0, fmask = 0;
  unsigned tcq[7];
#pragma unroll
  for (int k = 0; k < 7; ++k) tcq[k] = 0u;
  unsigned kreg[8];
  float at = 0.f, btp = 0.f, ct = 0.f, atf = 0.f, btf = 0.f, ctf = 0.f;
  float ak = 0.f, bk = 0.f, ck = 0.f;

  // grid.x = 200 -> exactly 2 float4-iters per thread
#pragma unroll
  for (int it = 0; it < 2; ++it) {
    const int i = it * 51200 + blockIdx.x * 256 + tid;
    float4 t4 = tx[i]; float4 q4 = kr[i]; int4 g4 = gt[i]; int4 k4 = gk[i]; float4 m4 = tmv[i];
#pragma unroll
    for (int j = 0; j < 4; ++j) {
      float tv = ((const float*)&t4)[j];
      float kv = ((const float*)&q4)[j];
      int gtv = ((const int*)&g4)[j];
      int gkv = ((const int*)&k4)[j];
      float mv = ((const float*)&m4)[j];
      bool pos = gtv > 0;
      bool mh = mv > 0.5f;
      cpos += pos;
      cposm += (pos && !mh);
      unsigned key = mapf(tv);
      kreg[it * 4 + j] = key;
      float sig = 1.f / (1.f + expf(-tv));
      if (!pos) {
        vmask |= 1u << (it * 4 + j);
        if (mh) fmask |= 1u << (it * 4 + j);
        atomicAdd(&sh_h[key >> 21], 1u);
      } else if (mh) {
        at += sig; btp += sig * sig; ct += 1.f;
      }
#pragma unroll
      for (int k = 0; k < 7; ++k)
        tcq[k] += (unsigned)__popcll(__ballot(gtv == k + 1));
      float sm = sig * mv;           // fallback dice (sel = tm float)
      btf += sm * sm;
      if (pos) { atf += sm * mv; ctf += mv * mv; }
      if ((tv > 0.f) && mh) {        // kernel dice
        float sk = 1.f / (1.f + expf(-kv));
        bk += sk * sk;
        if (gkv > 0) { ak += sk; ck += 1.f; }
      }
    }
  }

  unsigned r = wredu(cpos), r2 = wredu(cposm);
  if (lane == 0) { shC[w * 2] = r; shC[w * 2 + 1] = r2; }
  if (lane == 0) {
#pragma unroll
    for (int k = 0; k < 7; ++k) shTC[w * 7 + k] = tcq[k];
  }
  float v9[9] = {at, btp, ct, atf, btf, ctf, ak, bk, ck};
#pragma unroll
  for (int q = 0; q < 9; ++q) {
    float f = wredf(v9[q]);
    if (lane == 0) shRed[w * 9 + q] = f;
  }

  unsigned cnt = (unsigned)__popc(vmask), cntF = (unsigned)__popc(fmask);
  shScan[tid] = cnt | (cntF << 16);
  __syncthreads();
#pragma unroll
  for (int off = 1; off < 256; off <<= 1) {
    unsigned vv = (tid >= off) ? shScan[tid - off] : 0u;
    __syncthreads();
    shScan[tid] += vv;
    __syncthreads();
  }
  if (tid == 0) {
    unsigned tot = shScan[255];
    shBase[0] = atomicAdd(&wsb[OFF_KN], tot & 0xFFFFu);
    shBase[1] = atomicAdd(&wsb[OFF_KNF], tot >> 16);
  }
  for (int i = tid; i < 2048; i += 256) {
    unsigned h = sh_h[i]; if (h) atomicAdd(&wsb[OFF_H0 + i], h);
  }
  if (tid < 7) {
    unsigned s = shTC[tid] + shTC[7 + tid] + shTC[14 + tid] + shTC[21 + tid];
    if (s) atomicAdd(&wsb[OFF_TC + 1 + tid], s);
  } else if (tid >= 16 && tid < 25) {
    int q = tid - 16;
    float s = shRed[q] + shRed[9 + q] + shRed[18 + q] + shRed[27 + q];
    atomicAdd(&wsbf[OFF_DICE + q], s);
  } else if (tid == 30) {
    atomicAdd(&wsb[OFF_CPOS], shC[0] + shC[2] + shC[4] + shC[6]);
  } else if (tid == 31) {
    atomicAdd(&wsb[OFF_CPOSM], shC[1] + shC[3] + shC[5] + shC[7]);
  }
  __syncthreads();   // shBase ready
  unsigned gA = shBase[0] + (shScan[tid] & 0xFFFFu) - cnt;
  unsigned gF = shBase[1] + (shScan[tid] >> 16) - cntF;
  unsigned* keys = ws + KEYS_BASE + (size_t)b * NPIX;
#pragma unroll
  for (int s = 0; s < 8; ++s)
    if (vmask & (1u << s)) { keys[gA] = kreg[s]; ++gA; }
#pragma unroll
  for (int s = 0; s < 8; ++s)
    if (fmask & (1u << s)) { keys[NPIX - 1 - gF] = kreg[s]; ++gF; }
}

// ---- kS: per-instance sim sums (KS) + KC counts. R4-proven: private
//      per-thread LDS float4 slots, RMW without atomics; ballot for KC. -----
__global__ __launch_bounds__(256) void kS(const float* __restrict__ out_,
                                          const int* __restrict__ lab_,
                                          unsigned* __restrict__ ws) {
  const int b = blockIdx.y;
  unsigned* wsb = ws + (size_t)b * PER_BATCH;
  float* wsbf = (float*)wsb;
  __shared__ __align__(16) float L[8 * 257 * 4];   // 32.9 KB
  __shared__ float L2[32 * 8];
  __shared__ unsigned sh_kcw[4 * 7];
  const int tid = threadIdx.x, lane = tid & 63, w = tid >> 6;
  for (int i = tid; i < 8 * 257 * 4; i += 256) L[i] = 0.f;
  __syncthreads();

  const float4* s0 = (const float4*)(out_ + (size_t)b * 6 * NPIX + 2 * (size_t)NPIX);
  const float4* s1 = (const float4*)(out_ + (size_t)b * 6 * NPIX + 3 * (size_t)NPIX);
  const float4* s2 = (const float4*)(out_ + (size_t)b * 6 * NPIX + 4 * (size_t)NPIX);
  const float4* s3 = (const float4*)(out_ + (size_t)b * 6 * NPIX + 5 * (size_t)NPIX);
  const int4* gkk = (const int4*)(lab_ + (size_t)b * 2 * NPIX + NPIX);

  unsigned kcq[7];
#pragma unroll
  for (int k = 0; k < 7; ++k) kcq[k] = 0u;

  const int nv = NPIX / 4;
  for (int i = blockIdx.x * 256 + tid; i < nv; i += gridDim.x * 256) {
    int4 k4 = gkk[i];
    float4 a0 = s0[i], a1 = s1[i], a2 = s2[i], a3 = s3[i];
#pragma unroll
    for (int j = 0; j < 4; ++j) {
      int gkv = ((const int*)&k4)[j];
#pragma unroll
      for (int k = 0; k < 7; ++k)
        kcq[k] += (unsigned)__popcll(__ballot(gkv == k + 1));
      int idx = (gkv > 0) ? (gkv - 1) : 7;   // 7 = trash slot
      float4* slot = (float4*)&L[(idx * 257 + tid) * 4];
      float4 rr = *slot;
      rr.x += ((const float*)&a0)[j];
      rr.y += ((const float*)&a1)[j];
      rr.z += ((const float*)&a2)[j];
      rr.w += ((const float*)&a3)[j];
      *slot = rr;
    }
  }

  if (lane == 0) {
#pragma unroll
    for (int k = 0; k < 7; ++k) sh_kcw[w * 7 + k] = kcq[k];
  }
  __syncthreads();
  {
    int p = tid & 31, sub = tid >> 5;
    int idx = p & 7, c = p >> 3;
    float part = 0.f;
#pragma unroll
    for (int i = 0; i < 32; ++i) part += L[(idx * 257 + (sub + 8 * i)) * 4 + c];
    L2[p * 8 + sub] = part;
  }
  __syncthreads();
  if (tid < 32) {
    float s = 0.f;
#pragma unroll
    for (int q = 0; q < 8; ++q) s += L2[tid * 8 + q];
    int idx = tid & 7, c = tid >> 3;
    if (idx < 7 && s != 0.f) atomicAdd(&wsbf[OFF_KS + (idx + 1) * 4 + c], s);
  } else if (tid >= 64 && tid < 71) {
    int k = tid - 64;
    unsigned s = sh_kcw[k] + sh_kcw[7 + k] + sh_kcw[14 + k] + sh_kcw[21 + k];
    if (s) atomicAdd(&wsb[OFF_KC + 1 + k], s);
  }
}

// ---- kGSel: blocks 1..100 = agg (gt+sim, register accumulators);
//      block 0 = full selection (prologue + 3-level radix + bt_neg) ---------
__global__ __launch_bounds__(256) void kGSel(const float* __restrict__ out_,
                                             const int* __restrict__ lab_,
                                             unsigned* __restrict__ ws) {
  const int b = blockIdx.y;
  unsigned* wsb = ws + (size_t)b * PER_BATCH;
  float* wsbf = (float*)wsb;
  __shared__ unsigned U[2048];
  __shared__ unsigned S2[256];
  __shared__ float sG[32];
  __shared__ float sAgg[4 * 7];
  __shared__ unsigned sh_k, sh_pfx0, sh_pfx22, sh_thk;
  __shared__ int sh_fall;
  const int tid = threadIdx.x, lane = tid & 63, w = tid >> 6;

  if (blockIdx.x != 0) {
    // ================= agg role =================
    const int bx = blockIdx.x - 1;
    if (tid < 32) {
      int inst = tid >> 2, c = tid & 3;
      float g = 0.f;
      if (inst >= 1) {
        unsigned kc = wsb[OFF_KC + inst];
        g = wsbf[OFF_KS + inst * 4 + c] / fmaxf((float)kc, 1.f);
      }
      sG[tid] = g;
    }
    __syncthreads();
    const int4* gt = (const int4*)(lab_ + (size_t)b * 2 * NPIX);
    const float4* s0 = (const float4*)(out_ + (size_t)b * 6 * NPIX + 2 * (size_t)NPIX);
    const float4* s1 = (const float4*)(out_ + (size_t)b * 6 * NPIX + 3 * (size_t)NPIX);
    const float4* s2 = (const float4*)(out_ + (size_t)b * 6 * NPIX + 4 * (size_t)NPIX);
    const float4* s3 = (const float4*)(out_ + (size_t)b * 6 * NPIX + 5 * (size_t)NPIX);
    float agg[7];
#pragma unroll
    for (int k = 0; k < 7; ++k) agg[k] = 0.f;
#pragma unroll
    for (int it = 0; it < 4; ++it) {
      const int i = it * 25600 + bx * 256 + tid;
      int4 g4 = gt[i];
      float4 a0 = s0[i], a1 = s1[i], a2 = s2[i], a3 = s3[i];
#pragma unroll
      for (int j = 0; j < 4; ++j) {
        int gtv = ((const int*)&g4)[j];
        bool pos = gtv > 0;
        int kk = pos ? gtv : 0;
        float d0 = ((const float*)&a0)[j] - sG[kk * 4 + 0];
        float d1 = ((const float*)&a1)[j] - sG[kk * 4 + 1];
        float d2 = ((const float*)&a2)[j] - sG[kk * 4 + 2];
        float d3 = ((const float*)&a3)[j] - sG[kk * 4 + 3];
        float sq = d0 * d0 + d1 * d1 + d2 * d2 + d3 * d3;
        float d = (sq > 0.f) ? sqrtf(sq) : 0.f;
        float dd = fmaxf(d - 0.5f, 0.f);
        float lg = pos ? log1pf(dd * dd) : 0.f;
#pragma unroll
        for (int k = 0; k < 7; ++k) agg[k] += (gtv == k + 1) ? lg : 0.f;
      }
    }
#pragma unroll
    for (int k = 0; k < 7; ++k) {
      float f = wredf(agg[k]);
      if (lane == 0) sAgg[w * 7 + k] = f;
    }
    __syncthreads();
    if (tid < 7) {
      float s = sAgg[tid] + sAgg[7 + tid] + sAgg[14 + tid] + sAgg[21 + tid];
      if (s != 0.f) atomicAdd(&wsbf[OFF_AGG + 1 + tid], s);
    }
    return;
  }

  // ================= select role =================
  if (tid == 0) {
    unsigned cpos = wsb[OFF_CPOS], cposm = wsb[OFF_CPOSM];
    long posnum = (long)cpos - (long)cposm;
    long cneg = (long)NPIX - (long)cpos;
    long negnum = posnum * 3; if (negnum > cneg) negnum = cneg;
    int fall = (posnum == 0) || (negnum == 0);
    wsb[OFF_FALL] = (unsigned)fall;
    sh_fall = fall; sh_k = (unsigned)negnum;
    float G[8][4];
    unsigned nvv = 0, vm = 0;
    for (int k = 1; k < 8; ++k) {
      unsigned kc = wsb[OFF_KC + k], tc = wsb[OFF_TC + k];
      float inv = 1.f / fmaxf((float)kc, 1.f);
      for (int c = 0; c < 4; ++c) G[k][c] = wsbf[OFF_KS + k * 4 + c] * inv;
      if (kc > 0 && tc > 0) { vm |= 1u << k; ++nvv; }
    }
    wsb[OFF_NV] = nvv; wsb[OFF_VM] = vm;
    float s = 0.f;
    for (int i = 1; i < 8; ++i) {
      if (!((vm >> i) & 1)) continue;
      for (int j = i + 1; j < 8; ++j) {
        if (!((vm >> j) & 1)) continue;
        float sq = 0.f;
        for (int c = 0; c < 4; ++c) { float d = G[i][c] - G[j][c]; sq += d * d; }
        float gn = (sq > 0.f) ? sqrtf(sq) : 0.f;
        float dd = fmaxf(3.0f - gn, 0.f);
        s += log1pf(dd * dd);
      }
    }
    float denom = (float)(nvv * (nvv > 0 ? nvv - 1u : 0u));
    wsbf[OFF_LDIS] = (nvv > 1) ? (s / fmaxf(denom, 1.f)) : 0.f;
    if (fall) wsbf[OFF_BTN] = 0.f;
  }
  __syncthreads();
  if (sh_fall) return;
  const unsigned kn = wsb[OFF_KN], knF = wsb[OFF_KNF];
  const unsigned* keys = ws + KEYS_BASE + (size_t)b * NPIX;

  // ---- level 0 from global H0 ----
  unsigned myp = 0;
#pragma unroll
  for (int j = 0; j < 8; ++j) myp += wsb[OFF_H0 + tid * 8 + j];
  S2[tid] = myp;
  __syncthreads();
#pragma unroll
  for (int off = 1; off < 256; off <<= 1) {
    unsigned v = (tid + off < 256) ? S2[tid + off] : 0u;
    __syncthreads();
    S2[tid] += v;
    __syncthreads();
  }
  {
    unsigned k = sh_k;
    unsigned suf = S2[tid], sufn = suf - myp;
    __syncthreads();
    if (suf >= k && sufn < k) {
      unsigned kk = k - sufn;
      unsigned cum2 = 0; int bin = tid * 8;
#pragma unroll
      for (int j = 7; j >= 0; --j) {
        unsigned h = wsb[OFF_H0 + tid * 8 + j]; cum2 += h;
        if (cum2 >= kk) { bin = tid * 8 + j; kk -= (cum2 - h); break; }
      }
      sh_pfx0 = (unsigned)bin; sh_k = kk;
    }
  }
  __syncthreads();
  const unsigned pfx0 = sh_pfx0;

  // ---- level 1: bits 20..10 from key list A ----
  for (int i = tid; i < 2048; i += 256) U[i] = 0u;
  __syncthreads();
  for (unsigned q = tid; q * 4 < kn; q += 256) {
    uint4 k4 = ((const uint4*)keys)[q];
#pragma unroll
    for (int e = 0; e < 4; ++e) {
      unsigned idx = q * 4 + e;
      if (idx < kn) {
        unsigned key = ((const unsigned*)&k4)[e];
        if ((key >> 21) == pfx0) atomicAdd(&U[(key >> 10) & 0x7FFu], 1u);
      }
    }
  }
  __syncthreads();
  myp = 0;
#pragma unroll
  for (int j = 0; j < 8; ++j) myp += U[tid * 8 + j];
  S2[tid] = myp;
  __syncthreads();
#pragma unroll
  for (int off = 1; off < 256; off <<= 1) {
    unsigned v = (tid + off < 256) ? S2[tid + off] : 0u;
    __syncthreads();
    S2[tid] += v;
    __syncthreads();
  }
  {
    unsigned k = sh_k;
    unsigned suf = S2[tid], sufn = suf - myp;
    __syncthreads();
    if (suf >= k && sufn < k) {
      unsigned kk = k - sufn;
      unsigned cum2 = 0; int bin = tid * 8;
#pragma unroll
      for (int j = 7; j >= 0; --j) {
        unsigned h = U[tid * 8 + j]; cum2 += h;
        if (cum2 >= kk) { bin = tid * 8 + j; kk -= (cum2 - h); break; }
      }
      sh_pfx22 = (pfx0 << 11) | (unsigned)bin; sh_k = kk;
    }
  }
  __syncthreads();
  const unsigned pfx22 = sh_pfx22;

  // ---- level 2: bits 9..0 ----
  for (int i = tid; i < 1024; i += 256) U[i] = 0u;
  __syncthreads();
  for (unsigned q = tid; q * 4 < kn; q += 256) {
    uint4 k4 = ((const uint4*)keys)[q];
#pragma unroll
    for (int e = 0; e < 4; ++e) {
      unsigned idx = q * 4 + e;
      if (idx < kn) {
        unsigned key = ((const unsigned*)&k4)[e];
        if ((key >> 10) == pfx22) atomicAdd(&U[key & 0x3FFu], 1u);
      }
    }
  }
  __syncthreads();
  myp = 0;
#pragma unroll
  for (int j = 0; j < 4; ++j) myp += U[tid * 4 + j];
  S2[tid] = myp;
  __syncthreads();
#pragma unroll
  for (int off = 1; off < 256; off <<= 1) {
    unsigned v = (tid + off < 256) ? S2[tid + off] : 0u;
    __syncthreads();
    S2[tid] += v;
    __syncthreads();
  }
  {
    unsigned k = sh_k;
    unsigned suf = S2[tid], sufn = suf - myp;
    __syncthreads();
    if (suf >= k && sufn < k) {
      unsigned kk = k - sufn;
      unsigned cum2 = 0; int bin = tid * 4;
#pragma unroll
      for (int j = 3; j >= 0; --j) {
        unsigned h = U[tid * 4 + j]; cum2 += h;
        if (cum2 >= kk) { bin = tid * 4 + j; break; }
      }
      sh_thk = (pfx22 << 10) | (unsigned)bin;
    }
  }
  __syncthreads();
  const unsigned thkey = sh_thk;

  // ---- bt_neg over flagged list B ----
  float part = 0.f;
  for (unsigned i = tid; i < knF; i += 256) {
    unsigned key = keys[NPIX - knF + i];
    if (key >= thkey) {
      float tv = unmapf(key);
      float sg = 1.f / (1.f + expf(-tv));
      part += sg * sg;
    }
  }
  part = wredf(part);
  if (lane == 0) sAgg[w] = part;
  __syncthreads();
  if (tid == 0) wsbf[OFF_BTN] = sAgg[0] + sAgg[1] + sAgg[2] + sAgg[3];
}

// ---- kH: finalize 5 scalars -------------------------------------------------
__global__ void kH(const unsigned* __restrict__ ws, float* __restrict__ out) {
  __shared__ float sv[4][8];
  const int b = threadIdx.x;
  if (b < 8) {
    const unsigned* wsb = ws + (size_t)b * PER_BATCH;
    const float* wsbf = (const float*)wsb;
    int fall = (int)wsb[OFF_FALL];
    float at, bt, ct;
    if (fall) {
      at = wsbf[OFF_DICE + 3]; bt = wsbf[OFF_DICE + 4]; ct = wsbf[OFF_DICE + 5];
    } else {
      at = wsbf[OFF_DICE + 0];
      bt = wsbf[OFF_DICE + 1] + wsbf[OFF_BTN];
      ct = wsbf[OFF_DICE + 2];
    }
    float lt = 1.f - 2.f * at / ((bt + 1e-3f) + (ct + 1e-3f));
    float ak = wsbf[OFF_DICE + 6], bk = wsbf[OFF_DICE + 7] + 1e-3f, ck = wsbf[OFF_DICE + 8] + 1e-3f;
    float lk = 1.f - 2.f * ak / (bk + ck);
    unsigned vm = wsb[OFF_VM], nvv = wsb[OFF_NV];
    float s = 0.f;
    for (int k = 1; k < 8; ++k)
      if ((vm >> k) & 1) s += wsbf[OFF_AGG + k] / fmaxf((float)wsb[OFF_TC + k], 1.f);
    float la = s / fmaxf((float)nvv, 1.f);
    float ld = wsbf[OFF_LDIS];
    sv[0][b] = lt; sv[1][b] = lk; sv[2][b] = la; sv[3][b] = ld;
  }
  __syncthreads();
  if (threadIdx.x == 0) {
    float mt = 0.f, mk = 0.f, ma = 0.f, md = 0.f;
    for (int i = 0; i < 8; ++i) { mt += sv[0][i]; mk += sv[1][i]; ma += sv[2][i]; md += sv[3][i]; }
    mt *= 0.125f; mk *= 0.125f; ma *= 0.125f; md *= 0.125f;
    out[0] = mt + 0.5f * mk + 0.25f * (ma + md);
    out[1] = mt;
    out[2] = mk;
    out[3] = ma;
    out[4] = md;
  }
}

extern "C" void kernel_launch(void* const* d_in, const int* in_sizes, int n_in,
                              void* d_out, int out_size, void* d_ws, size_t ws_size,
                              hipStream_t stream) {
  const float* outputs = (const float*)d_in[0];
  const int* labels = (const int*)d_in[1];
  const float* tm = (const float*)d_in[2];
  unsigned* ws = (unsigned*)d_ws;
  float* out = (float*)d_out;

  dim3 blk(256);
  kZ<<<(HDR_WORDS + 255) / 256, blk, 0, stream>>>(ws);
  kX<<<dim3(200, NB), blk, 0, stream>>>(outputs, labels, tm, ws);
  kS<<<dim3(128, NB), blk, 0, stream>>>(outputs, labels, ws);
  kGSel<<<dim3(101, NB), blk, 0, stream>>>(outputs, labels, ws);
  kH<<<1, 64, 0, stream>>>(ws, out);
}

// Round 9
// 123.370 us; speedup vs baseline: 1.5835x; 1.1837x over previous
//
#include <hip/hip_runtime.h>

#define NPIX 409600   // 640*640
#define NB 8          // batch

// ---------------- workspace layout (4-byte words, per batch) ----------------
constexpr int OFF_H0   = 0;     // 2048 u32  level-0 histogram (key bits 31..21)
constexpr int OFF_KC   = 2048;  // 8 u32   kernel-mask counts (idx 1..7 used)
constexpr int OFF_TC   = 2056;  // 8 u32   text-mask counts
constexpr int OFF_KS   = 2064;  // 32 f32  kernel-mask sim sums (inst*4+c)
constexpr int OFF_AGG  = 2096;  // 8 f32   per-instance sum log1p(D)
constexpr int OFF_CPOS = 2104;  // u32
constexpr int OFF_CPOSM= 2105;  // u32  pos & tm<=0.5
constexpr int OFF_KN   = 2106;  // u32  compact neg-key count (list A)
constexpr int OFF_KNF  = 2107;  // u32  flagged neg-key count (list B)
constexpr int OFF_FALL = 2108;  // u32
constexpr int OFF_NV   = 2109;  // u32
constexpr int OFF_VM   = 2110;  // u32
constexpr int OFF_LDIS = 2111;  // f32
constexpr int OFF_BTN  = 2112;  // f32  bt_neg (threshold-dependent dice part)
constexpr int OFF_DICE = 2113;  // 9 f32: at,btp,ct, atf,btf,ctf, ak,bk,ck
constexpr int PER_BATCH= 2176;
constexpr int KEYS_BASE= NB * PER_BATCH;
constexpr int HDR_WORDS= NB * PER_BATCH;
// per-batch key region (NPIX words): list A (all negs) grows up from 0,
// list B (flagged negs) grows down from NPIX-1.

__device__ __forceinline__ unsigned mapf(float s) {
  unsigned b = __float_as_uint(s);
  return (b & 0x80000000u) ? ~b : (b | 0x80000000u);
}
__device__ __forceinline__ float unmapf(unsigned u) {
  return __uint_as_float((u & 0x80000000u) ? (u & 0x7FFFFFFFu) : ~u);
}
__device__ __forceinline__ float wredf(float v) {
#pragma unroll
  for (int m = 32; m >= 1; m >>= 1) v += __shfl_xor(v, m, 64);
  return v;
}
__device__ __forceinline__ unsigned wredu(unsigned v) {
#pragma unroll
  for (int m = 32; m >= 1; m >>= 1) v += (unsigned)__shfl_xor((int)v, m, 64);
  return v;
}

// ---- kZ: zero workspace header ---------------------------------------------
__global__ __launch_bounds__(256) void kZ(unsigned* __restrict__ ws) {
  int i = blockIdx.x * 256 + threadIdx.x;
  if (i < HDR_WORDS) ws[i] = 0u;
}

// ---- kX: tx,kr,gt,gk,tm -> hist0, cpos/cposm, TC (ballot), all
//      threshold-independent dice sums, dual register-resident compaction ----
__global__ __launch_bounds__(256) void kX(const float* __restrict__ out_,
                                          const int* __restrict__ lab_,
                                          const float* __restrict__ tm_,
                                          unsigned* __restrict__ ws) {
  const int b = blockIdx.y;
  unsigned* wsb = ws + (size_t)b * PER_BATCH;
  float* wsbf = (float*)wsb;
  __shared__ unsigned sh_h[2048];
  __shared__ unsigned shScan[256];
  __shared__ unsigned shTC[4 * 7];
  __shared__ float shRed[4 * 9];
  __shared__ unsigned shC[4 * 2];
  __shared__ unsigned shBase[2];
  const int tid = threadIdx.x, lane = tid & 63, w = tid >> 6;
  for (int i = tid; i < 2048; i += 256) sh_h[i] = 0u;
  __syncthreads();

  const float4* tx = (const float4*)(out_ + (size_t)b * 6 * NPIX);
  const float4* kr = (const float4*)(out_ + (size_t)b * 6 * NPIX + (size_t)NPIX);
  const int4* gt = (const int4*)(lab_ + (size_t)b * 2 * NPIX);
  const int4* gk = (const int4*)(lab_ + (size_t)b * 2 * NPIX + NPIX);
  const float4* tmv = (const float4*)(tm_ + (size_t)b * NPIX);

  unsigned cpos = 0, cposm = 0, vmask = 0, fmask = 0;
  unsigned tcq[7];
#pragma unroll
  for (int k = 0; k < 7; ++k) tcq[k] = 0u;
  unsigned kreg[8];
  float at = 0.f, btp = 0.f, ct = 0.f, atf = 0.f, btf = 0.f, ctf = 0.f;
  float ak = 0.f, bk = 0.f, ck = 0.f;

#pragma unroll
  for (int it = 0; it < 2; ++it) {
    const int i = it * 51200 + blockIdx.x * 256 + tid;
    float4 t4 = tx[i]; float4 q4 = kr[i]; int4 g4 = gt[i]; int4 k4 = gk[i]; float4 m4 = tmv[i];
#pragma unroll
    for (int j = 0; j < 4; ++j) {
      float tv = ((const float*)&t4)[j];
      float kv = ((const float*)&q4)[j];
      int gtv = ((const int*)&g4)[j];
      int gkv = ((const int*)&k4)[j];
      float mv = ((const float*)&m4)[j];
      bool pos = gtv > 0;
      bool mh = mv > 0.5f;
      cpos += pos;
      cposm += (pos && !mh);
      unsigned key = mapf(tv);
      kreg[it * 4 + j] = key;
      float sig = 1.f / (1.f + expf(-tv));
      if (!pos) {
        vmask |= 1u << (it * 4 + j);
        if (mh) fmask |= 1u << (it * 4 + j);
        atomicAdd(&sh_h[key >> 21], 1u);
      } else if (mh) {
        at += sig; btp += sig * sig; ct += 1.f;
      }
#pragma unroll
      for (int k = 0; k < 7; ++k)
        tcq[k] += (unsigned)__popcll(__ballot(gtv == k + 1));
      float sm = sig * mv;           // fallback dice (sel = tm float)
      btf += sm * sm;
      if (pos) { atf += sm * mv; ctf += mv * mv; }
      if ((tv > 0.f) && mh) {        // kernel dice
        float sk = 1.f / (1.f + expf(-kv));
        bk += sk * sk;
        if (gkv > 0) { ak += sk; ck += 1.f; }
      }
    }
  }

  unsigned r = wredu(cpos), r2 = wredu(cposm);
  if (lane == 0) { shC[w * 2] = r; shC[w * 2 + 1] = r2; }
  if (lane == 0) {
#pragma unroll
    for (int k = 0; k < 7; ++k) shTC[w * 7 + k] = tcq[k];
  }
  float v9[9] = {at, btp, ct, atf, btf, ctf, ak, bk, ck};
#pragma unroll
  for (int q = 0; q < 9; ++q) {
    float f = wredf(v9[q]);
    if (lane == 0) shRed[w * 9 + q] = f;
  }

  unsigned cnt = (unsigned)__popc(vmask), cntF = (unsigned)__popc(fmask);
  shScan[tid] = cnt | (cntF << 16);
  __syncthreads();
#pragma unroll
  for (int off = 1; off < 256; off <<= 1) {
    unsigned vv = (tid >= off) ? shScan[tid - off] : 0u;
    __syncthreads();
    shScan[tid] += vv;
    __syncthreads();
  }
  if (tid == 0) {
    unsigned tot = shScan[255];
    shBase[0] = atomicAdd(&wsb[OFF_KN], tot & 0xFFFFu);
    shBase[1] = atomicAdd(&wsb[OFF_KNF], tot >> 16);
  }
  for (int i = tid; i < 2048; i += 256) {
    unsigned h = sh_h[i]; if (h) atomicAdd(&wsb[OFF_H0 + i], h);
  }
  if (tid < 7) {
    unsigned s = shTC[tid] + shTC[7 + tid] + shTC[14 + tid] + shTC[21 + tid];
    if (s) atomicAdd(&wsb[OFF_TC + 1 + tid], s);
  } else if (tid >= 16 && tid < 25) {
    int q = tid - 16;
    float s = shRed[q] + shRed[9 + q] + shRed[18 + q] + shRed[27 + q];
    atomicAdd(&wsbf[OFF_DICE + q], s);
  } else if (tid == 30) {
    atomicAdd(&wsb[OFF_CPOS], shC[0] + shC[2] + shC[4] + shC[6]);
  } else if (tid == 31) {
    atomicAdd(&wsb[OFF_CPOSM], shC[1] + shC[3] + shC[5] + shC[7]);
  }
  __syncthreads();   // shBase ready
  unsigned gA = shBase[0] + (shScan[tid] & 0xFFFFu) - cnt;
  unsigned gF = shBase[1] + (shScan[tid] >> 16) - cntF;
  unsigned* keys = ws + KEYS_BASE + (size_t)b * NPIX;
#pragma unroll
  for (int s = 0; s < 8; ++s)
    if (vmask & (1u << s)) { keys[gA] = kreg[s]; ++gA; }
#pragma unroll
  for (int s = 0; s < 8; ++s)
    if (fmask & (1u << s)) { keys[NPIX - 1 - gF] = kreg[s]; ++gF; }
}

// ---- kS: per-instance sim sums (KS) + KC counts (R4-proven mechanics) ------
__global__ __launch_bounds__(256) void kS(const float* __restrict__ out_,
                                          const int* __restrict__ lab_,
                                          unsigned* __restrict__ ws) {
  const int b = blockIdx.y;
  unsigned* wsb = ws + (size_t)b * PER_BATCH;
  float* wsbf = (float*)wsb;
  __shared__ __align__(16) float L[8 * 257 * 4];   // 32.9 KB
  __shared__ float L2[32 * 8];
  __shared__ unsigned sh_kcw[4 * 7];
  const int tid = threadIdx.x, lane = tid & 63, w = tid >> 6;
  for (int i = tid; i < 8 * 257 * 4; i += 256) L[i] = 0.f;
  __syncthreads();

  const float4* s0 = (const float4*)(out_ + (size_t)b * 6 * NPIX + 2 * (size_t)NPIX);
  const float4* s1 = (const float4*)(out_ + (size_t)b * 6 * NPIX + 3 * (size_t)NPIX);
  const float4* s2 = (const float4*)(out_ + (size_t)b * 6 * NPIX + 4 * (size_t)NPIX);
  const float4* s3 = (const float4*)(out_ + (size_t)b * 6 * NPIX + 5 * (size_t)NPIX);
  const int4* gkk = (const int4*)(lab_ + (size_t)b * 2 * NPIX + NPIX);

  unsigned kcq[7];
#pragma unroll
  for (int k = 0; k < 7; ++k) kcq[k] = 0u;

  const int nv = NPIX / 4;
  for (int i = blockIdx.x * 256 + tid; i < nv; i += gridDim.x * 256) {
    int4 k4 = gkk[i];
    float4 a0 = s0[i], a1 = s1[i], a2 = s2[i], a3 = s3[i];
#pragma unroll
    for (int j = 0; j < 4; ++j) {
      int gkv = ((const int*)&k4)[j];
#pragma unroll
      for (int k = 0; k < 7; ++k)
        kcq[k] += (unsigned)__popcll(__ballot(gkv == k + 1));
      int idx = (gkv > 0) ? (gkv - 1) : 7;   // 7 = trash slot
      float4* slot = (float4*)&L[(idx * 257 + tid) * 4];
      float4 rr = *slot;
      rr.x += ((const float*)&a0)[j];
      rr.y += ((const float*)&a1)[j];
      rr.z += ((const float*)&a2)[j];
      rr.w += ((const float*)&a3)[j];
      *slot = rr;
    }
  }

  if (lane == 0) {
#pragma unroll
    for (int k = 0; k < 7; ++k) sh_kcw[w * 7 + k] = kcq[k];
  }
  __syncthreads();
  {
    int p = tid & 31, sub = tid >> 5;
    int idx = p & 7, c = p >> 3;
    float part = 0.f;
#pragma unroll
    for (int i = 0; i < 32; ++i) part += L[(idx * 257 + (sub + 8 * i)) * 4 + c];
    L2[p * 8 + sub] = part;
  }
  __syncthreads();
  if (tid < 32) {
    float s = 0.f;
#pragma unroll
    for (int q = 0; q < 8; ++q) s += L2[tid * 8 + q];
    int idx = tid & 7, c = tid >> 3;
    if (idx < 7 && s != 0.f) atomicAdd(&wsbf[OFF_KS + (idx + 1) * 4 + c], s);
  } else if (tid >= 64 && tid < 71) {
    int k = tid - 64;
    unsigned s = sh_kcw[k] + sh_kcw[7 + k] + sh_kcw[14 + k] + sh_kcw[21 + k];
    if (s) atomicAdd(&wsb[OFF_KC + 1 + k], s);
  }
}

// ---- kGSel: blocks 1..100 = agg; block 0 = selection with MLP-8 scans ------
__global__ __launch_bounds__(256) void kGSel(const float* __restrict__ out_,
                                             const int* __restrict__ lab_,
                                             unsigned* __restrict__ ws) {
  const int b = blockIdx.y;
  unsigned* wsb = ws + (size_t)b * PER_BATCH;
  float* wsbf = (float*)wsb;
  __shared__ unsigned U[2048];
  __shared__ unsigned S2[256];
  __shared__ float sG[32];
  __shared__ float sAgg[4 * 7];
  __shared__ unsigned sh_k, sh_pfx0, sh_pfx22, sh_thk;
  __shared__ int sh_fall;
  const int tid = threadIdx.x, lane = tid & 63, w = tid >> 6;

  if (blockIdx.x != 0) {
    // ================= agg role =================
    const int bx = blockIdx.x - 1;
    if (tid < 32) {
      int inst = tid >> 2, c = tid & 3;
      float g = 0.f;
      if (inst >= 1) {
        unsigned kc = wsb[OFF_KC + inst];
        g = wsbf[OFF_KS + inst * 4 + c] / fmaxf((float)kc, 1.f);
      }
      sG[tid] = g;
    }
    __syncthreads();
    const int4* gt = (const int4*)(lab_ + (size_t)b * 2 * NPIX);
    const float4* s0 = (const float4*)(out_ + (size_t)b * 6 * NPIX + 2 * (size_t)NPIX);
    const float4* s1 = (const float4*)(out_ + (size_t)b * 6 * NPIX + 3 * (size_t)NPIX);
    const float4* s2 = (const float4*)(out_ + (size_t)b * 6 * NPIX + 4 * (size_t)NPIX);
    const float4* s3 = (const float4*)(out_ + (size_t)b * 6 * NPIX + 5 * (size_t)NPIX);
    float agg[7];
#pragma unroll
    for (int k = 0; k < 7; ++k) agg[k] = 0.f;
#pragma unroll
    for (int it = 0; it < 4; ++it) {
      const int i = it * 25600 + bx * 256 + tid;
      int4 g4 = gt[i];
      float4 a0 = s0[i], a1 = s1[i], a2 = s2[i], a3 = s3[i];
#pragma unroll
      for (int j = 0; j < 4; ++j) {
        int gtv = ((const int*)&g4)[j];
        bool pos = gtv > 0;
        int kk = pos ? gtv : 0;
        float d0 = ((const float*)&a0)[j] - sG[kk * 4 + 0];
        float d1 = ((const float*)&a1)[j] - sG[kk * 4 + 1];
        float d2 = ((const float*)&a2)[j] - sG[kk * 4 + 2];
        float d3 = ((const float*)&a3)[j] - sG[kk * 4 + 3];
        float sq = d0 * d0 + d1 * d1 + d2 * d2 + d3 * d3;
        float d = (sq > 0.f) ? sqrtf(sq) : 0.f;
        float dd = fmaxf(d - 0.5f, 0.f);
        float lg = pos ? log1pf(dd * dd) : 0.f;
#pragma unroll
        for (int k = 0; k < 7; ++k) agg[k] += (gtv == k + 1) ? lg : 0.f;
      }
    }
#pragma unroll
    for (int k = 0; k < 7; ++k) {
      float f = wredf(agg[k]);
      if (lane == 0) sAgg[w * 7 + k] = f;
    }
    __syncthreads();
    if (tid < 7) {
      float s = sAgg[tid] + sAgg[7 + tid] + sAgg[14 + tid] + sAgg[21 + tid];
      if (s != 0.f) atomicAdd(&wsbf[OFF_AGG + 1 + tid], s);
    }
    return;
  }

  // ================= select role =================
  if (tid == 0) {
    unsigned cpos = wsb[OFF_CPOS], cposm = wsb[OFF_CPOSM];
    long posnum = (long)cpos - (long)cposm;
    long cneg = (long)NPIX - (long)cpos;
    long negnum = posnum * 3; if (negnum > cneg) negnum = cneg;
    int fall = (posnum == 0) || (negnum == 0);
    wsb[OFF_FALL] = (unsigned)fall;
    sh_fall = fall; sh_k = (unsigned)negnum;
    float G[8][4];
    unsigned nvv = 0, vm = 0;
    for (int k = 1; k < 8; ++k) {
      unsigned kc = wsb[OFF_KC + k], tc = wsb[OFF_TC + k];
      float inv = 1.f / fmaxf((float)kc, 1.f);
      for (int c = 0; c < 4; ++c) G[k][c] = wsbf[OFF_KS + k * 4 + c] * inv;
      if (kc > 0 && tc > 0) { vm |= 1u << k; ++nvv; }
    }
    wsb[OFF_NV] = nvv; wsb[OFF_VM] = vm;
    float s = 0.f;
    for (int i = 1; i < 8; ++i) {
      if (!((vm >> i) & 1)) continue;
      for (int j = i + 1; j < 8; ++j) {
        if (!((vm >> j) & 1)) continue;
        float sq = 0.f;
        for (int c = 0; c < 4; ++c) { float d = G[i][c] - G[j][c]; sq += d * d; }
        float gn = (sq > 0.f) ? sqrtf(sq) : 0.f;
        float dd = fmaxf(3.0f - gn, 0.f);
        s += log1pf(dd * dd);
      }
    }
    float denom = (float)(nvv * (nvv > 0 ? nvv - 1u : 0u));
    wsbf[OFF_LDIS] = (nvv > 1) ? (s / fmaxf(denom, 1.f)) : 0.f;
    if (fall) wsbf[OFF_BTN] = 0.f;
  }
  __syncthreads();
  if (sh_fall) return;
  const unsigned kn = wsb[OFF_KN], knF = wsb[OFF_KNF];
  const unsigned* keys = ws + KEYS_BASE + (size_t)b * NPIX;
  const uint4* keys4 = (const uint4*)keys;
  const unsigned kn4 = (kn + 3u) >> 2;

  // ---- level 0 from global H0 ----
  unsigned myp = 0;
#pragma unroll
  for (int j = 0; j < 8; ++j) myp += wsb[OFF_H0 + tid * 8 + j];
  S2[tid] = myp;
  __syncthreads();
#pragma unroll
  for (int off = 1; off < 256; off <<= 1) {
    unsigned v = (tid + off < 256) ? S2[tid + off] : 0u;
    __syncthreads();
    S2[tid] += v;
    __syncthreads();
  }
  {
    unsigned k = sh_k;
    unsigned suf = S2[tid], sufn = suf - myp;
    __syncthreads();
    if (suf >= k && sufn < k) {
      unsigned kk = k - sufn;
      unsigned cum2 = 0; int bin = tid * 8;
#pragma unroll
      for (int j = 7; j >= 0; --j) {
        unsigned h = wsb[OFF_H0 + tid * 8 + j]; cum2 += h;
        if (cum2 >= kk) { bin = tid * 8 + j; kk -= (cum2 - h); break; }
      }
      sh_pfx0 = (unsigned)bin; sh_k = kk;
    }
  }
  __syncthreads();
  const unsigned pfx0 = sh_pfx0;

  // ---- level 1: bits 20..10 from list A, MLP-8 batched loads ----
  for (int i = tid; i < 2048; i += 256) U[i] = 0u;
  __syncthreads();
  for (unsigned base = 0; base < kn4; base += 256u * 8u) {
    uint4 v[8];
#pragma unroll
    for (int u = 0; u < 8; ++u) {
      unsigned q = base + (unsigned)u * 256u + (unsigned)tid;
      if (q < kn4) v[u] = keys4[q];
    }
#pragma unroll
    for (int u = 0; u < 8; ++u) {
      unsigned q = base + (unsigned)u * 256u + (unsigned)tid;
      if (q < kn4) {
#pragma unroll
        for (int e = 0; e < 4; ++e) {
          unsigned idx = q * 4u + (unsigned)e;
          if (idx < kn) {
            unsigned key = ((const unsigned*)&v[u])[e];
            if ((key >> 21) == pfx0) atomicAdd(&U[(key >> 10) & 0x7FFu], 1u);
          }
        }
      }
    }
  }
  __syncthreads();
  myp = 0;
#pragma unroll
  for (int j = 0; j < 8; ++j) myp += U[tid * 8 + j];
  S2[tid] = myp;
  __syncthreads();
#pragma unroll
  for (int off = 1; off < 256; off <<= 1) {
    unsigned v = (tid + off < 256) ? S2[tid + off] : 0u;
    __syncthreads();
    S2[tid] += v;
    __syncthreads();
  }
  {
    unsigned k = sh_k;
    unsigned suf = S2[tid], sufn = suf - myp;
    __syncthreads();
    if (suf >= k && sufn < k) {
      unsigned kk = k - sufn;
      unsigned cum2 = 0; int bin = tid * 8;
#pragma unroll
      for (int j = 7; j >= 0; --j) {
        unsigned h = U[tid * 8 + j]; cum2 += h;
        if (cum2 >= kk) { bin = tid * 8 + j; kk -= (cum2 - h); break; }
      }
      sh_pfx22 = (pfx0 << 11) | (unsigned)bin; sh_k = kk;
    }
  }
  __syncthreads();
  const unsigned pfx22 = sh_pfx22;

  // ---- level 2: bits 9..0, MLP-8 ----
  for (int i = tid; i < 1024; i += 256) U[i] = 0u;
  __syncthreads();
  for (unsigned base = 0; base < kn4; base += 256u * 8u) {
    uint4 v[8];
#pragma unroll
    for (int u = 0; u < 8; ++u) {
      unsigned q = base + (unsigned)u * 256u + (unsigned)tid;
      if (q < kn4) v[u] = keys4[q];
    }
#pragma unroll
    for (int u = 0; u < 8; ++u) {
      unsigned q = base + (unsigned)u * 256u + (unsigned)tid;
      if (q < kn4) {
#pragma unroll
        for (int e = 0; e < 4; ++e) {
          unsigned idx = q * 4u + (unsigned)e;
          if (idx < kn) {
            unsigned key = ((const unsigned*)&v[u])[e];
            if ((key >> 10) == pfx22) atomicAdd(&U[key & 0x3FFu], 1u);
          }
        }
      }
    }
  }
  __syncthreads();
  myp = 0;
#pragma unroll
  for (int j = 0; j < 4; ++j) myp += U[tid * 4 + j];
  S2[tid] = myp;
  __syncthreads();
#pragma unroll
  for (int off = 1; off < 256; off <<= 1) {
    unsigned v = (tid + off < 256) ? S2[tid + off] : 0u;
    __syncthreads();
    S2[tid] += v;
    __syncthreads();
  }
  {
    unsigned k = sh_k;
    unsigned suf = S2[tid], sufn = suf - myp;
    __syncthreads();
    if (suf >= k && sufn < k) {
      unsigned kk = k - sufn;
      unsigned cum2 = 0; int bin = tid * 4;
#pragma unroll
      for (int j = 3; j >= 0; --j) {
        unsigned h = U[tid * 4 + j]; cum2 += h;
        if (cum2 >= kk) { bin = tid * 4 + j; break; }
      }
      sh_thk = (pfx22 << 10) | (unsigned)bin;
    }
  }
  __syncthreads();
  const unsigned thkey = sh_thk;

  // ---- bt_neg over flagged list B, MLP-8 ----
  const unsigned* listB = keys + (NPIX - knF);
  float part = 0.f;
  for (unsigned base = 0; base < knF; base += 256u * 8u) {
    unsigned kv[8];
#pragma unroll
    for (int u = 0; u < 8; ++u) {
      unsigned i = base + (unsigned)u * 256u + (unsigned)tid;
      kv[u] = (i < knF) ? listB[i] : 0u;
    }
#pragma unroll
    for (int u = 0; u < 8; ++u) {
      unsigned i = base + (unsigned)u * 256u + (unsigned)tid;
      if (i < knF && kv[u] >= thkey) {
        float tv = unmapf(kv[u]);
        float sg = 1.f / (1.f + expf(-tv));
        part += sg * sg;
      }
    }
  }
  part = wredf(part);
  if (lane == 0) sAgg[w] = part;
  __syncthreads();
  if (tid == 0) wsbf[OFF_BTN] = sAgg[0] + sAgg[1] + sAgg[2] + sAgg[3];
}

// ---- kH: finalize 5 scalars -------------------------------------------------
__global__ void kH(const unsigned* __restrict__ ws, float* __restrict__ out) {
  __shared__ float sv[4][8];
  const int b = threadIdx.x;
  if (b < 8) {
    const unsigned* wsb = ws + (size_t)b * PER_BATCH;
    const float* wsbf = (const float*)wsb;
    int fall = (int)wsb[OFF_FALL];
    float at, bt, ct;
    if (fall) {
      at = wsbf[OFF_DICE + 3]; bt = wsbf[OFF_DICE + 4]; ct = wsbf[OFF_DICE + 5];
    } else {
      at = wsbf[OFF_DICE + 0];
      bt = wsbf[OFF_DICE + 1] + wsbf[OFF_BTN];
      ct = wsbf[OFF_DICE + 2];
    }
    float lt = 1.f - 2.f * at / ((bt + 1e-3f) + (ct + 1e-3f));
    float ak = wsbf[OFF_DICE + 6], bk = wsbf[OFF_DICE + 7] + 1e-3f, ck = wsbf[OFF_DICE + 8] + 1e-3f;
    float lk = 1.f - 2.f * ak / (bk + ck);
    unsigned vm = wsb[OFF_VM], nvv = wsb[OFF_NV];
    float s = 0.f;
    for (int k = 1; k < 8; ++k)
      if ((vm >> k) & 1) s += wsbf[OFF_AGG + k] / fmaxf((float)wsb[OFF_TC + k], 1.f);
    float la = s / fmaxf((float)nvv, 1.f);
    float ld = wsbf[OFF_LDIS];
    sv[0][b] = lt; sv[1][b] = lk; sv[2][b] = la; sv[3][b] = ld;
  }
  __syncthreads();
  if (threadIdx.x == 0) {
    float mt = 0.f, mk = 0.f, ma = 0.f, md = 0.f;
    for (int i = 0; i < 8; ++i) { mt += sv[0][i]; mk += sv[1][i]; ma += sv[2][i]; md += sv[3][i]; }
    mt *= 0.125f; mk *= 0.125f; ma *= 0.125f; md *= 0.125f;
    out[0] = mt + 0.5f * mk + 0.25f * (ma + md);
    out[1] = mt;
    out[2] = mk;
    out[3] = ma;
    out[4] = md;
  }
}

extern "C" void kernel_launch(void* const* d_in, const int* in_sizes, int n_in,
                              void* d_out, int out_size, void* d_ws, size_t ws_size,
                              hipStream_t stream) {
  const float* outputs = (const float*)d_in[0];
  const int* labels = (const int*)d_in[1];
  const float* tm = (const float*)d_in[2];
  unsigned* ws = (unsigned*)d_ws;
  float* out = (float*)d_out;

  dim3 blk(256);
  kZ<<<(HDR_WORDS + 255) / 256, blk, 0, stream>>>(ws);
  kX<<<dim3(200, NB), blk, 0, stream>>>(outputs, labels, tm, ws);
  kS<<<dim3(128, NB), blk, 0, stream>>>(outputs, labels, ws);
  kGSel<<<dim3(101, NB), blk, 0, stream>>>(outputs, labels, ws);
  kH<<<1, 64, 0, stream>>>(ws, out);
}

// Round 10
// 113.642 us; speedup vs baseline: 1.7191x; 1.0856x over previous
//
#include <hip/hip_runtime.h>

#define NPIX 409600   // 640*640
#define NB 8          // batch

// ---------------- workspace layout (4-byte words, per batch) ----------------
constexpr int OFF_H0   = 0;     // 2048 u32  level-0 hist (key bits 31..21)
constexpr int OFF_H1   = 2048;  // 2048 u32  level-1 hist (bits 20..10)
constexpr int OFF_H2   = 4096;  // 1024 u32  level-2 hist (bits 9..0)
constexpr int OFF_KC   = 5120;  // 8 u32   kernel-mask counts
constexpr int OFF_TC   = 5128;  // 8 u32   text-mask counts
constexpr int OFF_KS   = 5136;  // 32 f32  kernel-mask sim sums (inst*4+c)
constexpr int OFF_AGG  = 5168;  // 8 f32   per-instance sum log1p(D)
constexpr int OFF_CPOS = 5176;  // u32
constexpr int OFF_CPOSM= 5177;  // u32
constexpr int OFF_KN   = 5178;  // u32  list-A count (all negs)
constexpr int OFF_KNF  = 5179;  // u32  list-B count (flagged negs)
constexpr int OFF_FALL = 5180;  // u32
constexpr int OFF_NV   = 5181;  // u32
constexpr int OFF_VM   = 5182;  // u32
constexpr int OFF_LDIS = 5183;  // f32
constexpr int OFF_BTN  = 5184;  // f32  bt_neg (threshold-dependent dice part)
constexpr int OFF_PFX0 = 5185;  // u32
constexpr int OFF_K1   = 5186;  // u32
constexpr int OFF_PFX22= 5187;  // u32
constexpr int OFF_K2   = 5188;  // u32
constexpr int OFF_THK  = 5189;  // u32  threshold key
constexpr int OFF_DICE = 5190;  // 9 f32: at,btp,ct, atf,btf,ctf, ak,bk,ck
constexpr int PER_BATCH= 5248;
constexpr int KEYS_BASE= NB * PER_BATCH;
constexpr int HDR_WORDS= NB * PER_BATCH;
// per-batch key region (NPIX words): list A grows up from 0,
// list B (flagged) grows down from NPIX-1.

__device__ __forceinline__ unsigned mapf(float s) {
  unsigned b = __float_as_uint(s);
  return (b & 0x80000000u) ? ~b : (b | 0x80000000u);
}
__device__ __forceinline__ float unmapf(unsigned u) {
  return __uint_as_float((u & 0x80000000u) ? (u & 0x7FFFFFFFu) : ~u);
}
__device__ __forceinline__ float wredf(float v) {
#pragma unroll
  for (int m = 32; m >= 1; m >>= 1) v += __shfl_xor(v, m, 64);
  return v;
}
__device__ __forceinline__ unsigned wredu(unsigned v) {
#pragma unroll
  for (int m = 32; m >= 1; m >>= 1) v += (unsigned)__shfl_xor((int)v, m, 64);
  return v;
}

// ---- kZ ---------------------------------------------------------------------
__global__ __launch_bounds__(256) void kZ(unsigned* __restrict__ ws) {
  int i = blockIdx.x * 256 + threadIdx.x;
  if (i < HDR_WORDS) ws[i] = 0u;
}

// ---- kX: hist0 + counters + TC + threshold-independent dice + compaction ----
__global__ __launch_bounds__(256) void kX(const float* __restrict__ out_,
                                          const int* __restrict__ lab_,
                                          const float* __restrict__ tm_,
                                          unsigned* __restrict__ ws) {
  const int b = blockIdx.y;
  unsigned* wsb = ws + (size_t)b * PER_BATCH;
  float* wsbf = (float*)wsb;
  __shared__ unsigned sh_h[2048];
  __shared__ unsigned shScan[256];
  __shared__ unsigned shTC[4 * 7];
  __shared__ float shRed[4 * 9];
  __shared__ unsigned shC[4 * 2];
  __shared__ unsigned shBase[2];
  const int tid = threadIdx.x, lane = tid & 63, w = tid >> 6;
  for (int i = tid; i < 2048; i += 256) sh_h[i] = 0u;
  __syncthreads();

  const float4* tx = (const float4*)(out_ + (size_t)b * 6 * NPIX);
  const float4* kr = (const float4*)(out_ + (size_t)b * 6 * NPIX + (size_t)NPIX);
  const int4* gt = (const int4*)(lab_ + (size_t)b * 2 * NPIX);
  const int4* gk = (const int4*)(lab_ + (size_t)b * 2 * NPIX + NPIX);
  const float4* tmv = (const float4*)(tm_ + (size_t)b * NPIX);

  unsigned cpos = 0, cposm = 0, vmask = 0, fmask = 0;
  unsigned tcq[7];
#pragma unroll
  for (int k = 0; k < 7; ++k) tcq[k] = 0u;
  unsigned kreg[8];
  float at = 0.f, btp = 0.f, ct = 0.f, atf = 0.f, btf = 0.f, ctf = 0.f;
  float ak = 0.f, bk = 0.f, ck = 0.f;

#pragma unroll
  for (int it = 0; it < 2; ++it) {
    const int i = it * 51200 + blockIdx.x * 256 + tid;
    float4 t4 = tx[i]; float4 q4 = kr[i]; int4 g4 = gt[i]; int4 k4 = gk[i]; float4 m4 = tmv[i];
#pragma unroll
    for (int j = 0; j < 4; ++j) {
      float tv = ((const float*)&t4)[j];
      float kv = ((const float*)&q4)[j];
      int gtv = ((const int*)&g4)[j];
      int gkv = ((const int*)&k4)[j];
      float mv = ((const float*)&m4)[j];
      bool pos = gtv > 0;
      bool mh = mv > 0.5f;
      cpos += pos;
      cposm += (pos && !mh);
      unsigned key = mapf(tv);
      kreg[it * 4 + j] = key;
      float sig = 1.f / (1.f + expf(-tv));
      if (!pos) {
        vmask |= 1u << (it * 4 + j);
        if (mh) fmask |= 1u << (it * 4 + j);
        atomicAdd(&sh_h[key >> 21], 1u);
      } else if (mh) {
        at += sig; btp += sig * sig; ct += 1.f;
      }
#pragma unroll
      for (int k = 0; k < 7; ++k)
        tcq[k] += (unsigned)__popcll(__ballot(gtv == k + 1));
      float sm = sig * mv;           // fallback dice (sel = tm float)
      btf += sm * sm;
      if (pos) { atf += sm * mv; ctf += mv * mv; }
      if ((tv > 0.f) && mh) {        // kernel dice
        float sk = 1.f / (1.f + expf(-kv));
        bk += sk * sk;
        if (gkv > 0) { ak += sk; ck += 1.f; }
      }
    }
  }

  unsigned r = wredu(cpos), r2 = wredu(cposm);
  if (lane == 0) { shC[w * 2] = r; shC[w * 2 + 1] = r2; }
  if (lane == 0) {
#pragma unroll
    for (int k = 0; k < 7; ++k) shTC[w * 7 + k] = tcq[k];
  }
  float v9[9] = {at, btp, ct, atf, btf, ctf, ak, bk, ck};
#pragma unroll
  for (int q = 0; q < 9; ++q) {
    float f = wredf(v9[q]);
    if (lane == 0) shRed[w * 9 + q] = f;
  }

  unsigned cnt = (unsigned)__popc(vmask), cntF = (unsigned)__popc(fmask);
  shScan[tid] = cnt | (cntF << 16);
  __syncthreads();
#pragma unroll
  for (int off = 1; off < 256; off <<= 1) {
    unsigned vv = (tid >= off) ? shScan[tid - off] : 0u;
    __syncthreads();
    shScan[tid] += vv;
    __syncthreads();
  }
  if (tid == 0) {
    unsigned tot = shScan[255];
    shBase[0] = atomicAdd(&wsb[OFF_KN], tot & 0xFFFFu);
    shBase[1] = atomicAdd(&wsb[OFF_KNF], tot >> 16);
  }
  for (int i = tid; i < 2048; i += 256) {
    unsigned h = sh_h[i]; if (h) atomicAdd(&wsb[OFF_H0 + i], h);
  }
  if (tid < 7) {
    unsigned s = shTC[tid] + shTC[7 + tid] + shTC[14 + tid] + shTC[21 + tid];
    if (s) atomicAdd(&wsb[OFF_TC + 1 + tid], s);
  } else if (tid >= 16 && tid < 25) {
    int q = tid - 16;
    float s = shRed[q] + shRed[9 + q] + shRed[18 + q] + shRed[27 + q];
    atomicAdd(&wsbf[OFF_DICE + q], s);
  } else if (tid == 30) {
    atomicAdd(&wsb[OFF_CPOS], shC[0] + shC[2] + shC[4] + shC[6]);
  } else if (tid == 31) {
    atomicAdd(&wsb[OFF_CPOSM], shC[1] + shC[3] + shC[5] + shC[7]);
  }
  __syncthreads();
  unsigned gA = shBase[0] + (shScan[tid] & 0xFFFFu) - cnt;
  unsigned gF = shBase[1] + (shScan[tid] >> 16) - cntF;
  unsigned* keys = ws + KEYS_BASE + (size_t)b * NPIX;
#pragma unroll
  for (int s = 0; s < 8; ++s)
    if (vmask & (1u << s)) { keys[gA] = kreg[s]; ++gA; }
#pragma unroll
  for (int s = 0; s < 8; ++s)
    if (fmask & (1u << s)) { keys[NPIX - 1 - gF] = kreg[s]; ++gF; }
}

// ---- kS: per-instance sim sums + KC (R4-proven private-slot mechanics) -----
__global__ __launch_bounds__(256) void kS(const float* __restrict__ out_,
                                          const int* __restrict__ lab_,
                                          unsigned* __restrict__ ws) {
  const int b = blockIdx.y;
  unsigned* wsb = ws + (size_t)b * PER_BATCH;
  float* wsbf = (float*)wsb;
  __shared__ __align__(16) float L[8 * 257 * 4];
  __shared__ float L2[32 * 8];
  __shared__ unsigned sh_kcw[4 * 7];
  const int tid = threadIdx.x, lane = tid & 63, w = tid >> 6;
  for (int i = tid; i < 8 * 257 * 4; i += 256) L[i] = 0.f;
  __syncthreads();

  const float4* s0 = (const float4*)(out_ + (size_t)b * 6 * NPIX + 2 * (size_t)NPIX);
  const float4* s1 = (const float4*)(out_ + (size_t)b * 6 * NPIX + 3 * (size_t)NPIX);
  const float4* s2 = (const float4*)(out_ + (size_t)b * 6 * NPIX + 4 * (size_t)NPIX);
  const float4* s3 = (const float4*)(out_ + (size_t)b * 6 * NPIX + 5 * (size_t)NPIX);
  const int4* gkk = (const int4*)(lab_ + (size_t)b * 2 * NPIX + NPIX);

  unsigned kcq[7];
#pragma unroll
  for (int k = 0; k < 7; ++k) kcq[k] = 0u;

  const int nv = NPIX / 4;
  for (int i = blockIdx.x * 256 + tid; i < nv; i += gridDim.x * 256) {
    int4 k4 = gkk[i];
    float4 a0 = s0[i], a1 = s1[i], a2 = s2[i], a3 = s3[i];
#pragma unroll
    for (int j = 0; j < 4; ++j) {
      int gkv = ((const int*)&k4)[j];
#pragma unroll
      for (int k = 0; k < 7; ++k)
        kcq[k] += (unsigned)__popcll(__ballot(gkv == k + 1));
      int idx = (gkv > 0) ? (gkv - 1) : 7;
      float4* slot = (float4*)&L[(idx * 257 + tid) * 4];
      float4 rr = *slot;
      rr.x += ((const float*)&a0)[j];
      rr.y += ((const float*)&a1)[j];
      rr.z += ((const float*)&a2)[j];
      rr.w += ((const float*)&a3)[j];
      *slot = rr;
    }
  }

  if (lane == 0) {
#pragma unroll
    for (int k = 0; k < 7; ++k) sh_kcw[w * 7 + k] = kcq[k];
  }
  __syncthreads();
  {
    int p = tid & 31, sub = tid >> 5;
    int idx = p & 7, c = p >> 3;
    float part = 0.f;
#pragma unroll
    for (int i = 0; i < 32; ++i) part += L[(idx * 257 + (sub + 8 * i)) * 4 + c];
    L2[p * 8 + sub] = part;
  }
  __syncthreads();
  if (tid < 32) {
    float s = 0.f;
#pragma unroll
    for (int q = 0; q < 8; ++q) s += L2[tid * 8 + q];
    int idx = tid & 7, c = tid >> 3;
    if (idx < 7 && s != 0.f) atomicAdd(&wsbf[OFF_KS + (idx + 1) * 4 + c], s);
  } else if (tid >= 64 && tid < 71) {
    int k = tid - 64;
    unsigned s = sh_kcw[k] + sh_kcw[7 + k] + sh_kcw[14 + k] + sh_kcw[21 + k];
    if (s) atomicAdd(&wsb[OFF_KC + 1 + k], s);
  }
}

// ---- kG: agg loss only (gt + sim), register accumulators -------------------
__global__ __launch_bounds__(256) void kG(const float* __restrict__ out_,
                                          const int* __restrict__ lab_,
                                          unsigned* __restrict__ ws) {
  const int b = blockIdx.y;
  unsigned* wsb = ws + (size_t)b * PER_BATCH;
  float* wsbf = (float*)wsb;
  __shared__ float sG[32];
  __shared__ float sAgg[4 * 7];
  const int tid = threadIdx.x, lane = tid & 63, w = tid >> 6;
  if (tid < 32) {
    int inst = tid >> 2, c = tid & 3;
    float g = 0.f;
    if (inst >= 1) {
      unsigned kc = wsb[OFF_KC + inst];
      g = wsbf[OFF_KS + inst * 4 + c] / fmaxf((float)kc, 1.f);
    }
    sG[tid] = g;
  }
  __syncthreads();
  const int4* gt = (const int4*)(lab_ + (size_t)b * 2 * NPIX);
  const float4* s0 = (const float4*)(out_ + (size_t)b * 6 * NPIX + 2 * (size_t)NPIX);
  const float4* s1 = (const float4*)(out_ + (size_t)b * 6 * NPIX + 3 * (size_t)NPIX);
  const float4* s2 = (const float4*)(out_ + (size_t)b * 6 * NPIX + 4 * (size_t)NPIX);
  const float4* s3 = (const float4*)(out_ + (size_t)b * 6 * NPIX + 5 * (size_t)NPIX);
  float agg[7];
#pragma unroll
  for (int k = 0; k < 7; ++k) agg[k] = 0.f;
#pragma unroll
  for (int it = 0; it < 4; ++it) {
    const int i = it * 25600 + blockIdx.x * 256 + tid;
    int4 g4 = gt[i];
    float4 a0 = s0[i], a1 = s1[i], a2 = s2[i], a3 = s3[i];
#pragma unroll
    for (int j = 0; j < 4; ++j) {
      int gtv = ((const int*)&g4)[j];
      bool pos = gtv > 0;
      int kk = pos ? gtv : 0;
      float d0 = ((const float*)&a0)[j] - sG[kk * 4 + 0];
      float d1 = ((const float*)&a1)[j] - sG[kk * 4 + 1];
      float d2 = ((const float*)&a2)[j] - sG[kk * 4 + 2];
      float d3 = ((const float*)&a3)[j] - sG[kk * 4 + 3];
      float sq = d0 * d0 + d1 * d1 + d2 * d2 + d3 * d3;
      float d = (sq > 0.f) ? sqrtf(sq) : 0.f;
      float dd = fmaxf(d - 0.5f, 0.f);
      float lg = pos ? log1pf(dd * dd) : 0.f;
#pragma unroll
      for (int k = 0; k < 7; ++k) agg[k] += (gtv == k + 1) ? lg : 0.f;
    }
  }
#pragma unroll
  for (int k = 0; k < 7; ++k) {
    float f = wredf(agg[k]);
    if (lane == 0) sAgg[w * 7 + k] = f;
  }
  __syncthreads();
  if (tid < 7) {
    float s = sAgg[tid] + sAgg[7 + tid] + sAgg[14 + tid] + sAgg[21 + tid];
    if (s != 0.f) atomicAdd(&wsbf[OFF_AGG + 1 + tid], s);
  }
}

// ---- kSelA: prologue + level-0 scan of H0 ----------------------------------
__global__ __launch_bounds__(256) void kSelA(unsigned* __restrict__ ws) {
  const int b = blockIdx.x;
  unsigned* wsb = ws + (size_t)b * PER_BATCH;
  float* wsbf = (float*)wsb;
  __shared__ unsigned S[256];
  __shared__ unsigned sh_k;
  __shared__ int sh_fall;
  const int tid = threadIdx.x;
  if (tid == 0) {
    unsigned cpos = wsb[OFF_CPOS], cposm = wsb[OFF_CPOSM];
    long posnum = (long)cpos - (long)cposm;
    long cneg = (long)NPIX - (long)cpos;
    long negnum = posnum * 3; if (negnum > cneg) negnum = cneg;
    int fall = (posnum == 0) || (negnum == 0);
    wsb[OFF_FALL] = (unsigned)fall;
    sh_fall = fall; sh_k = (unsigned)negnum;
    float G[8][4];
    unsigned nvv = 0, vm = 0;
    for (int k = 1; k < 8; ++k) {
      unsigned kc = wsb[OFF_KC + k], tc = wsb[OFF_TC + k];
      float inv = 1.f / fmaxf((float)kc, 1.f);
      for (int c = 0; c < 4; ++c) G[k][c] = wsbf[OFF_KS + k * 4 + c] * inv;
      if (kc > 0 && tc > 0) { vm |= 1u << k; ++nvv; }
    }
    wsb[OFF_NV] = nvv; wsb[OFF_VM] = vm;
    float s = 0.f;
    for (int i = 1; i < 8; ++i) {
      if (!((vm >> i) & 1)) continue;
      for (int j = i + 1; j < 8; ++j) {
        if (!((vm >> j) & 1)) continue;
        float sq = 0.f;
        for (int c = 0; c < 4; ++c) { float d = G[i][c] - G[j][c]; sq += d * d; }
        float gn = (sq > 0.f) ? sqrtf(sq) : 0.f;
        float dd = fmaxf(3.0f - gn, 0.f);
        s += log1pf(dd * dd);
      }
    }
    float denom = (float)(nvv * (nvv > 0 ? nvv - 1u : 0u));
    wsbf[OFF_LDIS] = (nvv > 1) ? (s / fmaxf(denom, 1.f)) : 0.f;
  }
  __syncthreads();
  if (sh_fall) return;
  unsigned myp = 0;
#pragma unroll
  for (int j = 0; j < 8; ++j) myp += wsb[OFF_H0 + tid * 8 + j];
  S[tid] = myp;
  __syncthreads();
#pragma unroll
  for (int off = 1; off < 256; off <<= 1) {
    unsigned v = (tid + off < 256) ? S[tid + off] : 0u;
    __syncthreads();
    S[tid] += v;
    __syncthreads();
  }
  unsigned k = sh_k;
  unsigned suf = S[tid], sufn = suf - myp;
  if (suf >= k && sufn < k) {
    unsigned kk = k - sufn;
    unsigned cum2 = 0; int bin = tid * 8;
#pragma unroll
    for (int j = 7; j >= 0; --j) {
      unsigned h = wsb[OFF_H0 + tid * 8 + j]; cum2 += h;
      if (cum2 >= kk) { bin = tid * 8 + j; kk -= (cum2 - h); break; }
    }
    wsb[OFF_PFX0] = (unsigned)bin;
    wsb[OFF_K1] = kk;
  }
}

// ---- kSelB: level-1 hist from list A (16 blocks/batch) ---------------------
__global__ __launch_bounds__(256) void kSelB(unsigned* __restrict__ ws) {
  const int b = blockIdx.y;
  unsigned* wsb = ws + (size_t)b * PER_BATCH;
  if (wsb[OFF_FALL]) return;
  const unsigned pfx = wsb[OFF_PFX0];
  const unsigned kn = wsb[OFF_KN];
  __shared__ unsigned sh_h[2048];
  for (int i = threadIdx.x; i < 2048; i += 256) sh_h[i] = 0u;
  __syncthreads();
  const unsigned* keys = ws + KEYS_BASE + (size_t)b * NPIX;
  for (unsigned i = blockIdx.x * 256 + threadIdx.x; i < kn; i += gridDim.x * 256) {
    unsigned key = keys[i];
    if ((key >> 21) == pfx) atomicAdd(&sh_h[(key >> 10) & 0x7FFu], 1u);
  }
  __syncthreads();
  for (int i = threadIdx.x; i < 2048; i += 256) {
    unsigned v = sh_h[i]; if (v) atomicAdd(&wsb[OFF_H1 + i], v);
  }
}

// ---- kSelC: scan H1 -> PFX22, K2 -------------------------------------------
__global__ __launch_bounds__(256) void kSelC(unsigned* __restrict__ ws) {
  const int b = blockIdx.x;
  unsigned* wsb = ws + (size_t)b * PER_BATCH;
  if (wsb[OFF_FALL]) return;
  __shared__ unsigned S[256];
  const int tid = threadIdx.x;
  unsigned myp = 0;
#pragma unroll
  for (int j = 0; j < 8; ++j) myp += wsb[OFF_H1 + tid * 8 + j];
  S[tid] = myp;
  __syncthreads();
#pragma unroll
  for (int off = 1; off < 256; off <<= 1) {
    unsigned v = (tid + off < 256) ? S[tid + off] : 0u;
    __syncthreads();
    S[tid] += v;
    __syncthreads();
  }
  unsigned k = wsb[OFF_K1];
  unsigned suf = S[tid], sufn = suf - myp;
  if (suf >= k && sufn < k) {
    unsigned kk = k - sufn;
    unsigned cum2 = 0; int bin = tid * 8;
#pragma unroll
    for (int j = 7; j >= 0; --j) {
      unsigned h = wsb[OFF_H1 + tid * 8 + j]; cum2 += h;
      if (cum2 >= kk) { bin = tid * 8 + j; kk -= (cum2 - h); break; }
    }
    wsb[OFF_PFX22] = (wsb[OFF_PFX0] << 11) | (unsigned)bin;
    wsb[OFF_K2] = kk;
  }
}

// ---- kSelD: level-2 hist from list A (16 blocks/batch) ---------------------
__global__ __launch_bounds__(256) void kSelD(unsigned* __restrict__ ws) {
  const int b = blockIdx.y;
  unsigned* wsb = ws + (size_t)b * PER_BATCH;
  if (wsb[OFF_FALL]) return;
  const unsigned pfx22 = wsb[OFF_PFX22];
  const unsigned kn = wsb[OFF_KN];
  __shared__ unsigned sh_h[1024];
  for (int i = threadIdx.x; i < 1024; i += 256) sh_h[i] = 0u;
  __syncthreads();
  const unsigned* keys = ws + KEYS_BASE + (size_t)b * NPIX;
  for (unsigned i = blockIdx.x * 256 + threadIdx.x; i < kn; i += gridDim.x * 256) {
    unsigned key = keys[i];
    if ((key >> 10) == pfx22) atomicAdd(&sh_h[key & 0x3FFu], 1u);
  }
  __syncthreads();
  for (int i = threadIdx.x; i < 1024; i += 256) {
    unsigned v = sh_h[i]; if (v) atomicAdd(&wsb[OFF_H2 + i], v);
  }
}

// ---- kSelE: scan H2 -> threshold key ---------------------------------------
__global__ __launch_bounds__(256) void kSelE(unsigned* __restrict__ ws) {
  const int b = blockIdx.x;
  unsigned* wsb = ws + (size_t)b * PER_BATCH;
  if (wsb[OFF_FALL]) return;
  __shared__ unsigned S[256];
  const int tid = threadIdx.x;
  unsigned myp = 0;
#pragma unroll
  for (int j = 0; j < 4; ++j) myp += wsb[OFF_H2 + tid * 4 + j];
  S[tid] = myp;
  __syncthreads();
#pragma unroll
  for (int off = 1; off < 256; off <<= 1) {
    unsigned v = (tid + off < 256) ? S[tid + off] : 0u;
    __syncthreads();
    S[tid] += v;
    __syncthreads();
  }
  unsigned k = wsb[OFF_K2];
  unsigned suf = S[tid], sufn = suf - myp;
  if (suf >= k && sufn < k) {
    unsigned kk = k - sufn;
    unsigned cum2 = 0; int bin = tid * 4;
#pragma unroll
    for (int j = 3; j >= 0; --j) {
      unsigned h = wsb[OFF_H2 + tid * 4 + j]; cum2 += h;
      if (cum2 >= kk) { bin = tid * 4 + j; break; }
    }
    wsb[OFF_THK] = (wsb[OFF_PFX22] << 10) | (unsigned)bin;
  }
}

// ---- kSelF: bt_neg over flagged list B (16 blocks/batch) -------------------
__global__ __launch_bounds__(256) void kSelF(unsigned* __restrict__ ws) {
  const int b = blockIdx.y;
  unsigned* wsb = ws + (size_t)b * PER_BATCH;
  float* wsbf = (float*)wsb;
  if (wsb[OFF_FALL]) return;
  const unsigned thkey = wsb[OFF_THK];
  const unsigned knF = wsb[OFF_KNF];
  __shared__ float sF[4];
  const int tid = threadIdx.x, lane = tid & 63, w = tid >> 6;
  const unsigned* listB = ws + KEYS_BASE + (size_t)b * NPIX + (NPIX - knF);
  float part = 0.f;
  for (unsigned i = blockIdx.x * 256 + tid; i < knF; i += gridDim.x * 256) {
    unsigned key = listB[i];
    if (key >= thkey) {
      float tv = unmapf(key);
      float sg = 1.f / (1.f + expf(-tv));
      part += sg * sg;
    }
  }
  part = wredf(part);
  if (lane == 0) sF[w] = part;
  __syncthreads();
  if (tid == 0) {
    float s = sF[0] + sF[1] + sF[2] + sF[3];
    if (s != 0.f) atomicAdd(&wsbf[OFF_BTN], s);
  }
}

// ---- kH: finalize 5 scalars -------------------------------------------------
__global__ void kH(const unsigned* __restrict__ ws, float* __restrict__ out) {
  __shared__ float sv[4][8];
  const int b = threadIdx.x;
  if (b < 8) {
    const unsigned* wsb = ws + (size_t)b * PER_BATCH;
    const float* wsbf = (const float*)wsb;
    int fall = (int)wsb[OFF_FALL];
    float at, bt, ct;
    if (fall) {
      at = wsbf[OFF_DICE + 3]; bt = wsbf[OFF_DICE + 4]; ct = wsbf[OFF_DICE + 5];
    } else {
      at = wsbf[OFF_DICE + 0];
      bt = wsbf[OFF_DICE + 1] + wsbf[OFF_BTN];
      ct = wsbf[OFF_DICE + 2];
    }
    float lt = 1.f - 2.f * at / ((bt + 1e-3f) + (ct + 1e-3f));
    float ak = wsbf[OFF_DICE + 6], bk = wsbf[OFF_DICE + 7] + 1e-3f, ck = wsbf[OFF_DICE + 8] + 1e-3f;
    float lk = 1.f - 2.f * ak / (bk + ck);
    unsigned vm = wsb[OFF_VM], nvv = wsb[OFF_NV];
    float s = 0.f;
    for (int k = 1; k < 8; ++k)
      if ((vm >> k) & 1) s += wsbf[OFF_AGG + k] / fmaxf((float)wsb[OFF_TC + k], 1.f);
    float la = s / fmaxf((float)nvv, 1.f);
    float ld = wsbf[OFF_LDIS];
    sv[0][b] = lt; sv[1][b] = lk; sv[2][b] = la; sv[3][b] = ld;
  }
  __syncthreads();
  if (threadIdx.x == 0) {
    float mt = 0.f, mk = 0.f, ma = 0.f, md = 0.f;
    for (int i = 0; i < 8; ++i) { mt += sv[0][i]; mk += sv[1][i]; ma += sv[2][i]; md += sv[3][i]; }
    mt *= 0.125f; mk *= 0.125f; ma *= 0.125f; md *= 0.125f;
    out[0] = mt + 0.5f * mk + 0.25f * (ma + md);
    out[1] = mt;
    out[2] = mk;
    out[3] = ma;
    out[4] = md;
  }
}

extern "C" void kernel_launch(void* const* d_in, const int* in_sizes, int n_in,
                              void* d_out, int out_size, void* d_ws, size_t ws_size,
                              hipStream_t stream) {
  const float* outputs = (const float*)d_in[0];
  const int* labels = (const int*)d_in[1];
  const float* tm = (const float*)d_in[2];
  unsigned* ws = (unsigned*)d_ws;
  float* out = (float*)d_out;

  dim3 blk(256);
  kZ<<<(HDR_WORDS + 255) / 256, blk, 0, stream>>>(ws);
  kX<<<dim3(200, NB), blk, 0, stream>>>(outputs, labels, tm, ws);
  kS<<<dim3(128, NB), blk, 0, stream>>>(outputs, labels, ws);
  kG<<<dim3(100, NB), blk, 0, stream>>>(outputs, labels, ws);
  kSelA<<<NB, blk, 0, stream>>>(ws);
  kSelB<<<dim3(16, NB), blk, 0, stream>>>(ws);
  kSelC<<<NB, blk, 0, stream>>>(ws);
  kSelD<<<dim3(16, NB), blk, 0, stream>>>(ws);
  kSelE<<<NB, blk, 0, stream>>>(ws);
  kSelF<<<dim3(16, NB), blk, 0, stream>>>(ws);
  kH<<<1, 64, 0, stream>>>(ws, out);
}

// Round 13
// 97.602 us; speedup vs baseline: 2.0016x; 1.1643x over previous
//
#include <hip/hip_runtime.h>

#define NPIX 409600   // 640*640
#define NB 8          // batch

// ---------------- workspace layout (4-byte words, per batch) ----------------
constexpr int OFF_H0   = 0;     // 2048 u32  level-0 hist (key bits 31..21)
constexpr int OFF_H1   = 2048;  // 2048 u32  level-1 hist (bits 20..10)
constexpr int OFF_H2   = 4096;  // 1024 u32  level-2 hist (bits 9..0)
constexpr int OFF_KC   = 5120;  // 8 u32   kernel-mask counts
constexpr int OFF_TC   = 5128;  // 8 u32   text-mask counts
constexpr int OFF_KS   = 5136;  // 32 f32  kernel-mask sim sums (inst*4+c)
constexpr int OFF_AGG  = 5168;  // 8 f32   per-instance sum log1p(D)
constexpr int OFF_CPOS = 5176;  // u32
constexpr int OFF_CPOSM= 5177;  // u32
constexpr int OFF_KN   = 5178;  // u32  list-A count (all negs)
constexpr int OFF_KNF  = 5179;  // u32  list-B count (flagged negs)
constexpr int OFF_FALL = 5180;  // u32
constexpr int OFF_NV   = 5181;  // u32
constexpr int OFF_VM   = 5182;  // u32
constexpr int OFF_LDIS = 5183;  // f32
constexpr int OFF_BTN  = 5184;  // f32  bt_neg (threshold-dependent dice part)
constexpr int OFF_PFX0 = 5185;  // u32
constexpr int OFF_K1   = 5186;  // u32
constexpr int OFF_PFX22= 5187;  // u32
constexpr int OFF_K2   = 5188;  // u32
constexpr int OFF_DICE = 5190;  // 9 f32: at,btp,ct, atf,btf,ctf, ak,bk,ck
constexpr int PER_BATCH= 5248;
constexpr int KEYS_BASE= NB * PER_BATCH;
constexpr int HDR_WORDS= NB * PER_BATCH;
// per-batch key region (NPIX words): list A grows up from 0,
// list B (flagged) grows down from NPIX-1.

__device__ __forceinline__ unsigned mapf(float s) {
  unsigned b = __float_as_uint(s);
  return (b & 0x80000000u) ? ~b : (b | 0x80000000u);
}
__device__ __forceinline__ float unmapf(unsigned u) {
  return __uint_as_float((u & 0x80000000u) ? (u & 0x7FFFFFFFu) : ~u);
}
__device__ __forceinline__ float wredf(float v) {
#pragma unroll
  for (int m = 32; m >= 1; m >>= 1) v += __shfl_xor(v, m, 64);
  return v;
}
__device__ __forceinline__ unsigned wredu(unsigned v) {
#pragma unroll
  for (int m = 32; m >= 1; m >>= 1) v += (unsigned)__shfl_xor((int)v, m, 64);
  return v;
}

// ---- kZ ---------------------------------------------------------------------
__global__ __launch_bounds__(256) void kZ(unsigned* __restrict__ ws) {
  int i = blockIdx.x * 256 + threadIdx.x;
  if (i < HDR_WORDS) ws[i] = 0u;
}

// ---- kXS: one launch, two block roles. LDS manually unioned (34 KB). -------
// role X (blocks 0..199): hist0 + counters + TC + threshold-independent dice
//   + dual register-resident key compaction (R10 kX verbatim).
// role S (blocks 200..327): per-instance sim sums + KC via private LDS
//   float4 slots (R10 kS verbatim, stride 128 blocks).
__global__ __launch_bounds__(256) void kXS(const float* __restrict__ out_,
                                           const int* __restrict__ lab_,
                                           const float* __restrict__ tm_,
                                           unsigned* __restrict__ ws) {
  const int b = blockIdx.y;
  unsigned* wsb = ws + (size_t)b * PER_BATCH;
  float* wsbf = (float*)wsb;
  __shared__ __align__(16) unsigned shm[8508];   // union of role layouts
  const int tid = threadIdx.x, lane = tid & 63, w = tid >> 6;

  if (blockIdx.x < 200) {
    // ========================= role X =========================
    const int bx = blockIdx.x;
    unsigned* sh_h   = shm;                   // 2048
    unsigned* shScan = shm + 2048;            // 256
    unsigned* shTC   = shm + 2304;            // 28
    float*    shRed  = (float*)(shm + 2336);  // 36
    unsigned* shC    = shm + 2372;            // 8
    unsigned* shBase = shm + 2380;            // 2
    for (int i = tid; i < 2048; i += 256) sh_h[i] = 0u;
    __syncthreads();

    const float4* tx = (const float4*)(out_ + (size_t)b * 6 * NPIX);
    const float4* kr = (const float4*)(out_ + (size_t)b * 6 * NPIX + (size_t)NPIX);
    const int4* gt = (const int4*)(lab_ + (size_t)b * 2 * NPIX);
    const int4* gk = (const int4*)(lab_ + (size_t)b * 2 * NPIX + NPIX);
    const float4* tmv = (const float4*)(tm_ + (size_t)b * NPIX);

    unsigned cpos = 0, cposm = 0, vmask = 0, fmask = 0;
    unsigned tcq[7];
#pragma unroll
    for (int k = 0; k < 7; ++k) tcq[k] = 0u;
    unsigned kreg[8];
    float at = 0.f, btp = 0.f, ct = 0.f, atf = 0.f, btf = 0.f, ctf = 0.f;
    float ak = 0.f, bk = 0.f, ck = 0.f;

#pragma unroll
    for (int it = 0; it < 2; ++it) {
      const int i = it * 51200 + bx * 256 + tid;
      float4 t4 = tx[i]; float4 q4 = kr[i]; int4 g4 = gt[i]; int4 k4 = gk[i]; float4 m4 = tmv[i];
#pragma unroll
      for (int j = 0; j < 4; ++j) {
        float tv = ((const float*)&t4)[j];
        float kv = ((const float*)&q4)[j];
        int gtv = ((const int*)&g4)[j];
        int gkv = ((const int*)&k4)[j];
        float mv = ((const float*)&m4)[j];
        bool pos = gtv > 0;
        bool mh = mv > 0.5f;
        cpos += pos;
        cposm += (pos && !mh);
        unsigned key = mapf(tv);
        kreg[it * 4 + j] = key;
        float sig = 1.f / (1.f + expf(-tv));
        if (!pos) {
          vmask |= 1u << (it * 4 + j);
          if (mh) fmask |= 1u << (it * 4 + j);
          atomicAdd(&sh_h[key >> 21], 1u);
        } else if (mh) {
          at += sig; btp += sig * sig; ct += 1.f;
        }
#pragma unroll
        for (int k = 0; k < 7; ++k)
          tcq[k] += (unsigned)__popcll(__ballot(gtv == k + 1));
        float sm = sig * mv;           // fallback dice (sel = tm float)
        btf += sm * sm;
        if (pos) { atf += sm * mv; ctf += mv * mv; }
        if ((tv > 0.f) && mh) {        // kernel dice
          float sk = 1.f / (1.f + expf(-kv));
          bk += sk * sk;
          if (gkv > 0) { ak += sk; ck += 1.f; }
        }
      }
    }

    unsigned r = wredu(cpos), r2 = wredu(cposm);
    if (lane == 0) { shC[w * 2] = r; shC[w * 2 + 1] = r2; }
    if (lane == 0) {
#pragma unroll
      for (int k = 0; k < 7; ++k) shTC[w * 7 + k] = tcq[k];
    }
    float v9[9] = {at, btp, ct, atf, btf, ctf, ak, bk, ck};
#pragma unroll
    for (int q = 0; q < 9; ++q) {
      float f = wredf(v9[q]);
      if (lane == 0) shRed[w * 9 + q] = f;
    }

    unsigned cnt = (unsigned)__popc(vmask), cntF = (unsigned)__popc(fmask);
    shScan[tid] = cnt | (cntF << 16);
    __syncthreads();
#pragma unroll
    for (int off = 1; off < 256; off <<= 1) {
      unsigned vv = (tid >= off) ? shScan[tid - off] : 0u;
      __syncthreads();
      shScan[tid] += vv;
      __syncthreads();
    }
    if (tid == 0) {
      unsigned tot = shScan[255];
      shBase[0] = atomicAdd(&wsb[OFF_KN], tot & 0xFFFFu);
      shBase[1] = atomicAdd(&wsb[OFF_KNF], tot >> 16);
    }
    for (int i = tid; i < 2048; i += 256) {
      unsigned h = sh_h[i]; if (h) atomicAdd(&wsb[OFF_H0 + i], h);
    }
    if (tid < 7) {
      unsigned s = shTC[tid] + shTC[7 + tid] + shTC[14 + tid] + shTC[21 + tid];
      if (s) atomicAdd(&wsb[OFF_TC + 1 + tid], s);
    } else if (tid >= 16 && tid < 25) {
      int q = tid - 16;
      float s = shRed[q] + shRed[9 + q] + shRed[18 + q] + shRed[27 + q];
      atomicAdd(&wsbf[OFF_DICE + q], s);
    } else if (tid == 30) {
      atomicAdd(&wsb[OFF_CPOS], shC[0] + shC[2] + shC[4] + shC[6]);
    } else if (tid == 31) {
      atomicAdd(&wsb[OFF_CPOSM], shC[1] + shC[3] + shC[5] + shC[7]);
    }
    __syncthreads();
    unsigned gA = shBase[0] + (shScan[tid] & 0xFFFFu) - cnt;
    unsigned gF = shBase[1] + (shScan[tid] >> 16) - cntF;
    unsigned* keys = ws + KEYS_BASE + (size_t)b * NPIX;
#pragma unroll
    for (int s = 0; s < 8; ++s)
      if (vmask & (1u << s)) { keys[gA] = kreg[s]; ++gA; }
#pragma unroll
    for (int s = 0; s < 8; ++s)
      if (fmask & (1u << s)) { keys[NPIX - 1 - gF] = kreg[s]; ++gF; }
  } else {
    // ========================= role S =========================
    const int bx = blockIdx.x - 200;
    float* L = (float*)shm;                  // 8224 words (8*257*4)
    float* L2 = (float*)(shm + 8224);        // 256
    unsigned* sh_kcw = shm + 8480;           // 28
    for (int i = tid; i < 8224; i += 256) L[i] = 0.f;
    __syncthreads();

    const float4* s0 = (const float4*)(out_ + (size_t)b * 6 * NPIX + 2 * (size_t)NPIX);
    const float4* s1 = (const float4*)(out_ + (size_t)b * 6 * NPIX + 3 * (size_t)NPIX);
    const float4* s2 = (const float4*)(out_ + (size_t)b * 6 * NPIX + 4 * (size_t)NPIX);
    const float4* s3 = (const float4*)(out_ + (size_t)b * 6 * NPIX + 5 * (size_t)NPIX);
    const int4* gkk = (const int4*)(lab_ + (size_t)b * 2 * NPIX + NPIX);

    unsigned kcq[7];
#pragma unroll
    for (int k = 0; k < 7; ++k) kcq[k] = 0u;

    const int nv = NPIX / 4;
    for (int i = bx * 256 + tid; i < nv; i += 128 * 256) {
      int4 k4 = gkk[i];
      float4 a0 = s0[i], a1 = s1[i], a2 = s2[i], a3 = s3[i];
#pragma unroll
      for (int j = 0; j < 4; ++j) {
        int gkv = ((const int*)&k4)[j];
#pragma unroll
        for (int k = 0; k < 7; ++k)
          kcq[k] += (unsigned)__popcll(__ballot(gkv == k + 1));
        int idx = (gkv > 0) ? (gkv - 1) : 7;
        float4* slot = (float4*)&L[(idx * 257 + tid) * 4];
        float4 rr = *slot;
        rr.x += ((const float*)&a0)[j];
        rr.y += ((const float*)&a1)[j];
        rr.z += ((const float*)&a2)[j];
        rr.w += ((const float*)&a3)[j];
        *slot = rr;
      }
    }

    if (lane == 0) {
#pragma unroll
      for (int k = 0; k < 7; ++k) sh_kcw[w * 7 + k] = kcq[k];
    }
    __syncthreads();
    {
      int p = tid & 31, sub = tid >> 5;
      int idx = p & 7, c = p >> 3;
      float part = 0.f;
#pragma unroll
      for (int i = 0; i < 32; ++i) part += L[(idx * 257 + (sub + 8 * i)) * 4 + c];
      L2[p * 8 + sub] = part;
    }
    __syncthreads();
    if (tid < 32) {
      float s = 0.f;
#pragma unroll
      for (int q = 0; q < 8; ++q) s += L2[tid * 8 + q];
      int idx = tid & 7, c = tid >> 3;
      if (idx < 7 && s != 0.f) atomicAdd(&wsbf[OFF_KS + (idx + 1) * 4 + c], s);
    } else if (tid >= 64 && tid < 71) {
      int k = tid - 64;
      unsigned s = sh_kcw[k] + sh_kcw[7 + k] + sh_kcw[14 + k] + sh_kcw[21 + k];
      if (s) atomicAdd(&wsb[OFF_KC + 1 + k], s);
    }
  }
}

// ---- kGB: role G (blocks 0..99) = agg loss; role B' (blocks 100..115) =
//      select prologue + H0 scan (redundant per block) + H1 hist ------------
__global__ __launch_bounds__(256) void kGB(const float* __restrict__ out_,
                                           const int* __restrict__ lab_,
                                           unsigned* __restrict__ ws) {
  const int b = blockIdx.y;
  unsigned* wsb = ws + (size_t)b * PER_BATCH;
  float* wsbf = (float*)wsb;
  const int tid = threadIdx.x, lane = tid & 63, w = tid >> 6;

  if (blockIdx.x < 100) {
    // ================= G role (R10 kG verbatim) =================
    __shared__ float sG[32];
    __shared__ float sAgg[4 * 7];
    const int bx = blockIdx.x;
    if (tid < 32) {
      int inst = tid >> 2, c = tid & 3;
      float g = 0.f;
      if (inst >= 1) {
        unsigned kc = wsb[OFF_KC + inst];
        g = wsbf[OFF_KS + inst * 4 + c] / fmaxf((float)kc, 1.f);
      }
      sG[tid] = g;
    }
    __syncthreads();
    const int4* gt = (const int4*)(lab_ + (size_t)b * 2 * NPIX);
    const float4* s0 = (const float4*)(out_ + (size_t)b * 6 * NPIX + 2 * (size_t)NPIX);
    const float4* s1 = (const float4*)(out_ + (size_t)b * 6 * NPIX + 3 * (size_t)NPIX);
    const float4* s2 = (const float4*)(out_ + (size_t)b * 6 * NPIX + 4 * (size_t)NPIX);
    const float4* s3 = (const float4*)(out_ + (size_t)b * 6 * NPIX + 5 * (size_t)NPIX);
    float agg[7];
#pragma unroll
    for (int k = 0; k < 7; ++k) agg[k] = 0.f;
#pragma unroll
    for (int it = 0; it < 4; ++it) {
      const int i = it * 25600 + bx * 256 + tid;
      int4 g4 = gt[i];
      float4 a0 = s0[i], a1 = s1[i], a2 = s2[i], a3 = s3[i];
#pragma unroll
      for (int j = 0; j < 4; ++j) {
        int gtv = ((const int*)&g4)[j];
        bool pos = gtv > 0;
        int kk = pos ? gtv : 0;
        float d0 = ((const float*)&a0)[j] - sG[kk * 4 + 0];
        float d1 = ((const float*)&a1)[j] - sG[kk * 4 + 1];
        float d2 = ((const float*)&a2)[j] - sG[kk * 4 + 2];
        float d3 = ((const float*)&a3)[j] - sG[kk * 4 + 3];
        float sq = d0 * d0 + d1 * d1 + d2 * d2 + d3 * d3;
        float d = (sq > 0.f) ? sqrtf(sq) : 0.f;
        float dd = fmaxf(d - 0.5f, 0.f);
        float lg = pos ? log1pf(dd * dd) : 0.f;
#pragma unroll
        for (int k = 0; k < 7; ++k) agg[k] += (gtv == k + 1) ? lg : 0.f;
      }
    }
#pragma unroll
    for (int k = 0; k < 7; ++k) {
      float f = wredf(agg[k]);
      if (lane == 0) sAgg[w * 7 + k] = f;
    }
    __syncthreads();
    if (tid < 7) {
      float s = sAgg[tid] + sAgg[7 + tid] + sAgg[14 + tid] + sAgg[21 + tid];
      if (s != 0.f) atomicAdd(&wsbf[OFF_AGG + 1 + tid], s);
    }
  } else {
    // ================= B' role =================
    const int bb = blockIdx.x - 100;   // 0..15
    __shared__ unsigned S[256];
    __shared__ unsigned sh_h1[2048];
    __shared__ unsigned sh_k, sh_pfx0;
    __shared__ int sh_fall;
    if (tid == 0) {
      unsigned cpos = wsb[OFF_CPOS], cposm = wsb[OFF_CPOSM];
      long posnum = (long)cpos - (long)cposm;
      long cneg = (long)NPIX - (long)cpos;
      long negnum = posnum * 3; if (negnum > cneg) negnum = cneg;
      int fall = (posnum == 0) || (negnum == 0);
      wsb[OFF_FALL] = (unsigned)fall;
      sh_fall = fall; sh_k = (unsigned)negnum;
      float G[8][4];
      unsigned nvv = 0, vm = 0;
      for (int k = 1; k < 8; ++k) {
        unsigned kc = wsb[OFF_KC + k], tc = wsb[OFF_TC + k];
        float inv = 1.f / fmaxf((float)kc, 1.f);
        for (int c = 0; c < 4; ++c) G[k][c] = wsbf[OFF_KS + k * 4 + c] * inv;
        if (kc > 0 && tc > 0) { vm |= 1u << k; ++nvv; }
      }
      wsb[OFF_NV] = nvv; wsb[OFF_VM] = vm;
      float s = 0.f;
      for (int i = 1; i < 8; ++i) {
        if (!((vm >> i) & 1)) continue;
        for (int j = i + 1; j < 8; ++j) {
          if (!((vm >> j) & 1)) continue;
          float sq = 0.f;
          for (int c = 0; c < 4; ++c) { float d = G[i][c] - G[j][c]; sq += d * d; }
          float gn = (sq > 0.f) ? sqrtf(sq) : 0.f;
          float dd = fmaxf(3.0f - gn, 0.f);
          s += log1pf(dd * dd);
        }
      }
      float denom = (float)(nvv * (nvv > 0 ? nvv - 1u : 0u));
      wsbf[OFF_LDIS] = (nvv > 1) ? (s / fmaxf(denom, 1.f)) : 0.f;
    }
    __syncthreads();
    if (sh_fall) return;
    // redundant H0 suffix-scan per block -> pfx0, k1
    unsigned myp = 0;
#pragma unroll
    for (int j = 0; j < 8; ++j) myp += wsb[OFF_H0 + tid * 8 + j];
    S[tid] = myp;
    __syncthreads();
#pragma unroll
    for (int off = 1; off < 256; off <<= 1) {
      unsigned v = (tid + off < 256) ? S[tid + off] : 0u;
      __syncthreads();
      S[tid] += v;
      __syncthreads();
    }
    {
      unsigned k = sh_k;
      unsigned suf = S[tid], sufn = suf - myp;
      if (suf >= k && sufn < k) {
        unsigned kk = k - sufn;
        unsigned cum2 = 0; int bin = tid * 8;
#pragma unroll
        for (int j = 7; j >= 0; --j) {
          unsigned h = wsb[OFF_H0 + tid * 8 + j]; cum2 += h;
          if (cum2 >= kk) { bin = tid * 8 + j; kk -= (cum2 - h); break; }
        }
        sh_pfx0 = (unsigned)bin;
        wsb[OFF_PFX0] = (unsigned)bin;   // dup same-value writes: benign
        wsb[OFF_K1] = kk;
      }
    }
    __syncthreads();
    const unsigned pfx = sh_pfx0;
    const unsigned kn = wsb[OFF_KN];
    for (int i = tid; i < 2048; i += 256) sh_h1[i] = 0u;
    __syncthreads();
    const unsigned* keys = ws + KEYS_BASE + (size_t)b * NPIX;
    for (unsigned i = bb * 256u + tid; i < kn; i += 16u * 256u) {
      unsigned key = keys[i];
      if ((key >> 21) == pfx) atomicAdd(&sh_h1[(key >> 10) & 0x7FFu], 1u);
    }
    __syncthreads();
    for (int i = tid; i < 2048; i += 256) {
      unsigned v = sh_h1[i]; if (v) atomicAdd(&wsb[OFF_H1 + i], v);
    }
  }
}

// ---- kCD: 16 blocks/batch. Redundant H1 scan -> pfx22,k2; then H2 hist -----
__global__ __launch_bounds__(256) void kCD(unsigned* __restrict__ ws) {
  const int b = blockIdx.y;
  unsigned* wsb = ws + (size_t)b * PER_BATCH;
  if (wsb[OFF_FALL]) return;
  __shared__ unsigned S[256];
  __shared__ unsigned sh_h2[1024];
  __shared__ unsigned sh_p22;
  const int tid = threadIdx.x;
  unsigned myp = 0;
#pragma unroll
  for (int j = 0; j < 8; ++j) myp += wsb[OFF_H1 + tid * 8 + j];
  S[tid] = myp;
  __syncthreads();
#pragma unroll
  for (int off = 1; off < 256; off <<= 1) {
    unsigned v = (tid + off < 256) ? S[tid + off] : 0u;
    __syncthreads();
    S[tid] += v;
    __syncthreads();
  }
  {
    unsigned k = wsb[OFF_K1];
    unsigned suf = S[tid], sufn = suf - myp;
    if (suf >= k && sufn < k) {
      unsigned kk = k - sufn;
      unsigned cum2 = 0; int bin = tid * 8;
#pragma unroll
      for (int j = 7; j >= 0; --j) {
        unsigned h = wsb[OFF_H1 + tid * 8 + j]; cum2 += h;
        if (cum2 >= kk) { bin = tid * 8 + j; kk -= (cum2 - h); break; }
      }
      unsigned p22 = (wsb[OFF_PFX0] << 11) | (unsigned)bin;
      sh_p22 = p22;
      wsb[OFF_PFX22] = p22;   // dup same-value writes: benign
      wsb[OFF_K2] = kk;
    }
  }
  __syncthreads();
  const unsigned pfx22 = sh_p22;
  const unsigned kn = wsb[OFF_KN];
  for (int i = tid; i < 1024; i += 256) sh_h2[i] = 0u;
  __syncthreads();
  const unsigned* keys = ws + KEYS_BASE + (size_t)b * NPIX;
  for (unsigned i = blockIdx.x * 256u + tid; i < kn; i += 16u * 256u) {
    unsigned key = keys[i];
    if ((key >> 10) == pfx22) atomicAdd(&sh_h2[key & 0x3FFu], 1u);
  }
  __syncthreads();
  for (int i = tid; i < 1024; i += 256) {
    unsigned v = sh_h2[i]; if (v) atomicAdd(&wsb[OFF_H2 + i], v);
  }
}

// ---- kEF: 16 blocks/batch. Redundant H2 scan -> thkey; then bt_neg ---------
__global__ __launch_bounds__(256) void kEF(unsigned* __restrict__ ws) {
  const int b = blockIdx.y;
  unsigned* wsb = ws + (size_t)b * PER_BATCH;
  float* wsbf = (float*)wsb;
  if (wsb[OFF_FALL]) return;
  __shared__ unsigned S[256];
  __shared__ unsigned sh_thk;
  __shared__ float sF[4];
  const int tid = threadIdx.x, lane = tid & 63, w = tid >> 6;
  unsigned myp = 0;
#pragma unroll
  for (int j = 0; j < 4; ++j) myp += wsb[OFF_H2 + tid * 4 + j];
  S[tid] = myp;
  __syncthreads();
#pragma unroll
  for (int off = 1; off < 256; off <<= 1) {
    unsigned v = (tid + off < 256) ? S[tid + off] : 0u;
    __syncthreads();
    S[tid] += v;
    __syncthreads();
  }
  {
    unsigned k = wsb[OFF_K2];
    unsigned suf = S[tid], sufn = suf - myp;
    if (suf >= k && sufn < k) {
      unsigned kk = k - sufn;
      unsigned cum2 = 0; int bin = tid * 4;
#pragma unroll
      for (int j = 3; j >= 0; --j) {
        unsigned h = wsb[OFF_H2 + tid * 4 + j]; cum2 += h;
        if (cum2 >= kk) { bin = tid * 4 + j; break; }
      }
      sh_thk = (wsb[OFF_PFX22] << 10) | (unsigned)bin;
    }
  }
  __syncthreads();
  const unsigned thkey = sh_thk;
  const unsigned knF = wsb[OFF_KNF];
  const unsigned* listB = ws + KEYS_BASE + (size_t)b * NPIX + (NPIX - knF);
  float part = 0.f;
  for (unsigned i = blockIdx.x * 256u + tid; i < knF; i += 16u * 256u) {
    unsigned key = listB[i];
    if (key >= thkey) {
      float tv = unmapf(key);
      float sg = 1.f / (1.f + expf(-tv));
      part += sg * sg;
    }
  }
  part = wredf(part);
  if (lane == 0) sF[w] = part;
  __syncthreads();
  if (tid == 0) {
    float s = sF[0] + sF[1] + sF[2] + sF[3];
    if (s != 0.f) atomicAdd(&wsbf[OFF_BTN], s);
  }
}

// ---- kH: finalize 5 scalars -------------------------------------------------
__global__ void kH(const unsigned* __restrict__ ws, float* __restrict__ out) {
  __shared__ float sv[4][8];
  const int b = threadIdx.x;
  if (b < 8) {
    const unsigned* wsb = ws + (size_t)b * PER_BATCH;
    const float* wsbf = (const float*)wsb;
    int fall = (int)wsb[OFF_FALL];
    float at, bt, ct;
    if (fall) {
      at = wsbf[OFF_DICE + 3]; bt = wsbf[OFF_DICE + 4]; ct = wsbf[OFF_DICE + 5];
    } else {
      at = wsbf[OFF_DICE + 0];
      bt = wsbf[OFF_DICE + 1] + wsbf[OFF_BTN];
      ct = wsbf[OFF_DICE + 2];
    }
    float lt = 1.f - 2.f * at / ((bt + 1e-3f) + (ct + 1e-3f));
    float ak = wsbf[OFF_DICE + 6], bk = wsbf[OFF_DICE + 7] + 1e-3f, ck = wsbf[OFF_DICE + 8] + 1e-3f;
    float lk = 1.f - 2.f * ak / (bk + ck);
    unsigned vm = wsb[OFF_VM], nvv = wsb[OFF_NV];
    float s = 0.f;
    for (int k = 1; k < 8; ++k)
      if ((vm >> k) & 1) s += wsbf[OFF_AGG + k] / fmaxf((float)wsb[OFF_TC + k], 1.f);
    float la = s / fmaxf((float)nvv, 1.f);
    float ld = wsbf[OFF_LDIS];
    sv[0][b] = lt; sv[1][b] = lk; sv[2][b] = la; sv[3][b] = ld;
  }
  __syncthreads();
  if (threadIdx.x == 0) {
    float mt = 0.f, mk = 0.f, ma = 0.f, md = 0.f;
    for (int i = 0; i < 8; ++i) { mt += sv[0][i]; mk += sv[1][i]; ma += sv[2][i]; md += sv[3][i]; }
    mt *= 0.125f; mk *= 0.125f; ma *= 0.125f; md *= 0.125f;
    out[0] = mt + 0.5f * mk + 0.25f * (ma + md);
    out[1] = mt;
    out[2] = mk;
    out[3] = ma;
    out[4] = md;
  }
}

extern "C" void kernel_launch(void* const* d_in, const int* in_sizes, int n_in,
                              void* d_out, int out_size, void* d_ws, size_t ws_size,
                              hipStream_t stream) {
  const float* outputs = (const float*)d_in[0];
  const int* labels = (const int*)d_in[1];
  const float* tm = (const float*)d_in[2];
  unsigned* ws = (unsigned*)d_ws;
  float* out = (float*)d_out;

  dim3 blk(256);
  kZ<<<(HDR_WORDS + 255) / 256, blk, 0, stream>>>(ws);
  kXS<<<dim3(328, NB), blk, 0, stream>>>(outputs, labels, tm, ws);
  kGB<<<dim3(116, NB), blk, 0, stream>>>(outputs, labels, ws);
  kCD<<<dim3(16, NB), blk, 0, stream>>>(ws);
  kEF<<<dim3(16, NB), blk, 0, stream>>>(ws);
  kH<<<1, 64, 0, stream>>>(ws, out);
}

// Round 14
// 88.538 us; speedup vs baseline: 2.2065x; 1.1024x over previous
//
#include <hip/hip_runtime.h>

#define NPIX 409600   // 640*640
#define NB 8          // batch

// ---------------- workspace layout (4-byte words, per batch) ----------------
constexpr int OFF_H0   = 0;     // 2048 u32  level-0 hist (key bits 31..21)
constexpr int OFF_H1   = 2048;  // 2048 u32  level-1 hist (bits 20..10)
constexpr int OFF_H2   = 4096;  // 1024 u32  level-2 hist (bits 9..0)
constexpr int OFF_KC   = 5120;  // 8 u32   kernel-mask counts
constexpr int OFF_TC   = 5128;  // 8 u32   text-mask counts
constexpr int OFF_KS   = 5136;  // 32 f32  kernel-mask sim sums (inst*4+c)
constexpr int OFF_AGG  = 5168;  // 8 f32   per-instance sum log1p(D)
constexpr int OFF_CPOS = 5176;  // u32
constexpr int OFF_CPOSM= 5177;  // u32
constexpr int OFF_KN   = 5178;  // u32  list-A count (all negs)
constexpr int OFF_KNF  = 5179;  // u32  list-B count (flagged negs)
constexpr int OFF_FALL = 5180;  // u32
constexpr int OFF_NV   = 5181;  // u32
constexpr int OFF_VM   = 5182;  // u32
constexpr int OFF_LDIS = 5183;  // f32
constexpr int OFF_BTN  = 5184;  // f32  bt_neg (threshold-dependent dice part)
constexpr int OFF_PFX0 = 5185;  // u32
constexpr int OFF_K1   = 5186;  // u32
constexpr int OFF_PFX22= 5187;  // u32
constexpr int OFF_K2   = 5188;  // u32
constexpr int OFF_DICE = 5190;  // 9 f32: at,btp,ct, atf,btf,ctf, ak,bk,ck
constexpr int PER_BATCH= 5248;
constexpr int KEYS_BASE= NB * PER_BATCH;
constexpr int HDR_WORDS= NB * PER_BATCH;
// per-batch key region (NPIX words): list A grows up from 0,
// list B (flagged) grows down from NPIX-1.

__device__ __forceinline__ unsigned mapf(float s) {
  unsigned b = __float_as_uint(s);
  return (b & 0x80000000u) ? ~b : (b | 0x80000000u);
}
__device__ __forceinline__ float unmapf(unsigned u) {
  return __uint_as_float((u & 0x80000000u) ? (u & 0x7FFFFFFFu) : ~u);
}
__device__ __forceinline__ float sigf(float x) {
  return __fdividef(1.f, 1.f + __expf(-x));
}
__device__ __forceinline__ float wredf(float v) {
#pragma unroll
  for (int m = 32; m >= 1; m >>= 1) v += __shfl_xor(v, m, 64);
  return v;
}
__device__ __forceinline__ unsigned wredu(unsigned v) {
#pragma unroll
  for (int m = 32; m >= 1; m >>= 1) v += (unsigned)__shfl_xor((int)v, m, 64);
  return v;
}

// ---- kZ ---------------------------------------------------------------------
__global__ __launch_bounds__(256) void kZ(unsigned* __restrict__ ws) {
  int i = blockIdx.x * 256 + threadIdx.x;
  if (i < HDR_WORDS) ws[i] = 0u;
}

// ---- kXS: one launch, three block roles. Union LDS 17.6 KB -> 8 blk/CU. ----
// role X  (blocks 0..199):  hist0 + counters + TC + thr-independent dice
//                           + dual register-resident key compaction.
// role S01 (200..327): sim c0/c1 sums + KC via private float2 LDS slots.
// role S23 (328..455): sim c2/c3 sums (no KC — S01 owns it).
__global__ __launch_bounds__(256) void kXS(const float* __restrict__ out_,
                                           const int* __restrict__ lab_,
                                           const float* __restrict__ tm_,
                                           unsigned* __restrict__ ws) {
  const int b = blockIdx.y;
  unsigned* wsb = ws + (size_t)b * PER_BATCH;
  float* wsbf = (float*)wsb;
  __shared__ __align__(16) unsigned shm[4412];   // union of role layouts
  const int tid = threadIdx.x, lane = tid & 63, w = tid >> 6;

  if (blockIdx.x < 200) {
    // ========================= role X =========================
    const int bx = blockIdx.x;
    unsigned* sh_h   = shm;                   // 2048
    unsigned* shScan = shm + 2048;            // 256
    unsigned* shTC   = shm + 2304;            // 28
    float*    shRed  = (float*)(shm + 2336);  // 36
    unsigned* shC    = shm + 2372;            // 8
    unsigned* shBase = shm + 2380;            // 2
    for (int i = tid; i < 2048; i += 256) sh_h[i] = 0u;
    __syncthreads();

    const float4* tx = (const float4*)(out_ + (size_t)b * 6 * NPIX);
    const float4* kr = (const float4*)(out_ + (size_t)b * 6 * NPIX + (size_t)NPIX);
    const int4* gt = (const int4*)(lab_ + (size_t)b * 2 * NPIX);
    const int4* gk = (const int4*)(lab_ + (size_t)b * 2 * NPIX + NPIX);
    const float4* tmv = (const float4*)(tm_ + (size_t)b * NPIX);

    unsigned cpos = 0, cposm = 0, vmask = 0, fmask = 0;
    unsigned tcq[7];
#pragma unroll
    for (int k = 0; k < 7; ++k) tcq[k] = 0u;
    unsigned kreg[8];
    float at = 0.f, btp = 0.f, ct = 0.f, atf = 0.f, btf = 0.f, ctf = 0.f;
    float ak = 0.f, bk = 0.f, ck = 0.f;

#pragma unroll
    for (int it = 0; it < 2; ++it) {
      const int i = it * 51200 + bx * 256 + tid;
      float4 t4 = tx[i]; float4 q4 = kr[i]; int4 g4 = gt[i]; int4 k4 = gk[i]; float4 m4 = tmv[i];
#pragma unroll
      for (int j = 0; j < 4; ++j) {
        float tv = ((const float*)&t4)[j];
        float kv = ((const float*)&q4)[j];
        int gtv = ((const int*)&g4)[j];
        int gkv = ((const int*)&k4)[j];
        float mv = ((const float*)&m4)[j];
        bool pos = gtv > 0;
        bool mh = mv > 0.5f;
        cpos += pos;
        cposm += (pos && !mh);
        unsigned key = mapf(tv);
        kreg[it * 4 + j] = key;
        float sig = sigf(tv);
        if (!pos) {
          vmask |= 1u << (it * 4 + j);
          if (mh) fmask |= 1u << (it * 4 + j);
          atomicAdd(&sh_h[key >> 21], 1u);
        } else if (mh) {
          at += sig; btp += sig * sig; ct += 1.f;
        }
#pragma unroll
        for (int k = 0; k < 7; ++k)
          tcq[k] += (unsigned)__popcll(__ballot(gtv == k + 1));
        float sm = sig * mv;           // fallback dice (sel = tm float)
        btf += sm * sm;
        if (pos) { atf += sm * mv; ctf += mv * mv; }
        if ((tv > 0.f) && mh) {        // kernel dice
          float sk = sigf(kv);
          bk += sk * sk;
          if (gkv > 0) { ak += sk; ck += 1.f; }
        }
      }
    }

    unsigned r = wredu(cpos), r2 = wredu(cposm);
    if (lane == 0) { shC[w * 2] = r; shC[w * 2 + 1] = r2; }
    if (lane == 0) {
#pragma unroll
      for (int k = 0; k < 7; ++k) shTC[w * 7 + k] = tcq[k];
    }
    float v9[9] = {at, btp, ct, atf, btf, ctf, ak, bk, ck};
#pragma unroll
    for (int q = 0; q < 9; ++q) {
      float f = wredf(v9[q]);
      if (lane == 0) shRed[w * 9 + q] = f;
    }

    unsigned cnt = (unsigned)__popc(vmask), cntF = (unsigned)__popc(fmask);
    shScan[tid] = cnt | (cntF << 16);
    __syncthreads();
#pragma unroll
    for (int off = 1; off < 256; off <<= 1) {
      unsigned vv = (tid >= off) ? shScan[tid - off] : 0u;
      __syncthreads();
      shScan[tid] += vv;
      __syncthreads();
    }
    if (tid == 0) {
      unsigned tot = shScan[255];
      shBase[0] = atomicAdd(&wsb[OFF_KN], tot & 0xFFFFu);
      shBase[1] = atomicAdd(&wsb[OFF_KNF], tot >> 16);
    }
    for (int i = tid; i < 2048; i += 256) {
      unsigned h = sh_h[i]; if (h) atomicAdd(&wsb[OFF_H0 + i], h);
    }
    if (tid < 7) {
      unsigned s = shTC[tid] + shTC[7 + tid] + shTC[14 + tid] + shTC[21 + tid];
      if (s) atomicAdd(&wsb[OFF_TC + 1 + tid], s);
    } else if (tid >= 16 && tid < 25) {
      int q = tid - 16;
      float s = shRed[q] + shRed[9 + q] + shRed[18 + q] + shRed[27 + q];
      atomicAdd(&wsbf[OFF_DICE + q], s);
    } else if (tid == 30) {
      atomicAdd(&wsb[OFF_CPOS], shC[0] + shC[2] + shC[4] + shC[6]);
    } else if (tid == 31) {
      atomicAdd(&wsb[OFF_CPOSM], shC[1] + shC[3] + shC[5] + shC[7]);
    }
    __syncthreads();
    unsigned gA = shBase[0] + (shScan[tid] & 0xFFFFu) - cnt;
    unsigned gF = shBase[1] + (shScan[tid] >> 16) - cntF;
    unsigned* keys = ws + KEYS_BASE + (size_t)b * NPIX;
#pragma unroll
    for (int s = 0; s < 8; ++s)
      if (vmask & (1u << s)) { keys[gA] = kreg[s]; ++gA; }
#pragma unroll
    for (int s = 0; s < 8; ++s)
      if (fmask & (1u << s)) { keys[NPIX - 1 - gF] = kreg[s]; ++gF; }
  } else {
    // ==================== role S01 / S23 ====================
    const bool lo = blockIdx.x < 328;    // channels {0,1} : {2,3}
    const int bx = lo ? (blockIdx.x - 200) : (blockIdx.x - 328);
    float* L = (float*)shm;              // 8*257*2 = 4112 words
    float* L2 = (float*)(shm + 4112);    // 16*17 = 272
    unsigned* sh_kcw = shm + 4384;       // 28
    for (int i = tid; i < 4112; i += 256) L[i] = 0.f;
    __syncthreads();

    const float4* sa = (const float4*)(out_ + (size_t)b * 6 * NPIX + (size_t)(lo ? 2 : 4) * NPIX);
    const float4* sb = (const float4*)(out_ + (size_t)b * 6 * NPIX + (size_t)(lo ? 3 : 5) * NPIX);
    const int4* gkk = (const int4*)(lab_ + (size_t)b * 2 * NPIX + NPIX);

    unsigned kcq[7];
#pragma unroll
    for (int k = 0; k < 7; ++k) kcq[k] = 0u;

    const int nv = NPIX / 4;
    for (int i = bx * 256 + tid; i < nv; i += 128 * 256) {
      int4 k4 = gkk[i];
      float4 a0 = sa[i], a1 = sb[i];
#pragma unroll
      for (int j = 0; j < 4; ++j) {
        int gkv = ((const int*)&k4)[j];
        if (lo) {
#pragma unroll
          for (int k = 0; k < 7; ++k)
            kcq[k] += (unsigned)__popcll(__ballot(gkv == k + 1));
        }
        int idx = (gkv > 0) ? (gkv - 1) : 7;   // 7 = trash slot
        float2* slot = (float2*)&L[(idx * 257 + tid) * 2];
        float2 rr = *slot;
        rr.x += ((const float*)&a0)[j];
        rr.y += ((const float*)&a1)[j];
        *slot = rr;
      }
    }

    if (lo && lane == 0) {
#pragma unroll
      for (int k = 0; k < 7; ++k) sh_kcw[w * 7 + k] = kcq[k];
    }
    __syncthreads();
    {
      int p = tid & 15, sub = tid >> 4;    // 16 planes x 16 subs
      int idx = p & 7, c = (p >> 3) & 1;
      float part = 0.f;
#pragma unroll
      for (int q = 0; q < 16; ++q) part += L[(idx * 257 + (sub + 16 * q)) * 2 + c];
      L2[p * 17 + sub] = part;
    }
    __syncthreads();
    if (tid < 16) {
      float s = 0.f;
#pragma unroll
      for (int q = 0; q < 16; ++q) s += L2[tid * 17 + q];
      int idx = tid & 7, c = (tid >> 3) & 1;
      if (idx < 7 && s != 0.f)
        atomicAdd(&wsbf[OFF_KS + (idx + 1) * 4 + (lo ? 0 : 2) + c], s);
    } else if (lo && tid >= 64 && tid < 71) {
      int k = tid - 64;
      unsigned s = sh_kcw[k] + sh_kcw[7 + k] + sh_kcw[14 + k] + sh_kcw[21 + k];
      if (s) atomicAdd(&wsb[OFF_KC + 1 + k], s);
    }
  }
}

// ---- kGB: role G (blocks 0..199) = agg loss (2 iters); role B'
//      (200..215) = select prologue + H0 scan + H1 hist ---------------------
__global__ __launch_bounds__(256) void kGB(const float* __restrict__ out_,
                                           const int* __restrict__ lab_,
                                           unsigned* __restrict__ ws) {
  const int b = blockIdx.y;
  unsigned* wsb = ws + (size_t)b * PER_BATCH;
  float* wsbf = (float*)wsb;
  const int tid = threadIdx.x, lane = tid & 63, w = tid >> 6;

  if (blockIdx.x < 200) {
    // ================= G role =================
    __shared__ float sG[32];
    __shared__ float sAgg[4 * 7];
    const int bx = blockIdx.x;
    if (tid < 32) {
      int inst = tid >> 2, c = tid & 3;
      float g = 0.f;
      if (inst >= 1) {
        unsigned kc = wsb[OFF_KC + inst];
        g = wsbf[OFF_KS + inst * 4 + c] / fmaxf((float)kc, 1.f);
      }
      sG[tid] = g;
    }
    __syncthreads();
    const int4* gt = (const int4*)(lab_ + (size_t)b * 2 * NPIX);
    const float4* s0 = (const float4*)(out_ + (size_t)b * 6 * NPIX + 2 * (size_t)NPIX);
    const float4* s1 = (const float4*)(out_ + (size_t)b * 6 * NPIX + 3 * (size_t)NPIX);
    const float4* s2 = (const float4*)(out_ + (size_t)b * 6 * NPIX + 4 * (size_t)NPIX);
    const float4* s3 = (const float4*)(out_ + (size_t)b * 6 * NPIX + 5 * (size_t)NPIX);
    float agg[7];
#pragma unroll
    for (int k = 0; k < 7; ++k) agg[k] = 0.f;
#pragma unroll
    for (int it = 0; it < 2; ++it) {
      const int i = it * 51200 + bx * 256 + tid;
      int4 g4 = gt[i];
      float4 a0 = s0[i], a1 = s1[i], a2 = s2[i], a3 = s3[i];
#pragma unroll
      for (int j = 0; j < 4; ++j) {
        int gtv = ((const int*)&g4)[j];
        bool pos = gtv > 0;
        int kk = pos ? gtv : 0;
        float d0 = ((const float*)&a0)[j] - sG[kk * 4 + 0];
        float d1 = ((const float*)&a1)[j] - sG[kk * 4 + 1];
        float d2 = ((const float*)&a2)[j] - sG[kk * 4 + 2];
        float d3 = ((const float*)&a3)[j] - sG[kk * 4 + 3];
        float sq = d0 * d0 + d1 * d1 + d2 * d2 + d3 * d3;
        float d = (sq > 0.f) ? sqrtf(sq) : 0.f;
        float dd = fmaxf(d - 0.5f, 0.f);
        float lg = pos ? __logf(1.f + dd * dd) : 0.f;
#pragma unroll
        for (int k = 0; k < 7; ++k) agg[k] += (gtv == k + 1) ? lg : 0.f;
      }
    }
#pragma unroll
    for (int k = 0; k < 7; ++k) {
      float f = wredf(agg[k]);
      if (lane == 0) sAgg[w * 7 + k] = f;
    }
    __syncthreads();
    if (tid < 7) {
      float s = sAgg[tid] + sAgg[7 + tid] + sAgg[14 + tid] + sAgg[21 + tid];
      if (s != 0.f) atomicAdd(&wsbf[OFF_AGG + 1 + tid], s);
    }
  } else {
    // ================= B' role =================
    const int bb = blockIdx.x - 200;   // 0..15
    __shared__ unsigned S[256];
    __shared__ unsigned sh_h1[2048];
    __shared__ unsigned sh_k, sh_pfx0;
    __shared__ int sh_fall;
    if (tid == 0) {
      unsigned cpos = wsb[OFF_CPOS], cposm = wsb[OFF_CPOSM];
      long posnum = (long)cpos - (long)cposm;
      long cneg = (long)NPIX - (long)cpos;
      long negnum = posnum * 3; if (negnum > cneg) negnum = cneg;
      int fall = (posnum == 0) || (negnum == 0);
      wsb[OFF_FALL] = (unsigned)fall;
      sh_fall = fall; sh_k = (unsigned)negnum;
      float G[8][4];
      unsigned nvv = 0, vm = 0;
      for (int k = 1; k < 8; ++k) {
        unsigned kc = wsb[OFF_KC + k], tc = wsb[OFF_TC + k];
        float inv = 1.f / fmaxf((float)kc, 1.f);
        for (int c = 0; c < 4; ++c) G[k][c] = wsbf[OFF_KS + k * 4 + c] * inv;
        if (kc > 0 && tc > 0) { vm |= 1u << k; ++nvv; }
      }
      wsb[OFF_NV] = nvv; wsb[OFF_VM] = vm;
      float s = 0.f;
      for (int i = 1; i < 8; ++i) {
        if (!((vm >> i) & 1)) continue;
        for (int j = i + 1; j < 8; ++j) {
          if (!((vm >> j) & 1)) continue;
          float sq = 0.f;
          for (int c = 0; c < 4; ++c) { float d = G[i][c] - G[j][c]; sq += d * d; }
          float gn = (sq > 0.f) ? sqrtf(sq) : 0.f;
          float dd = fmaxf(3.0f - gn, 0.f);
          s += log1pf(dd * dd);
        }
      }
      float denom = (float)(nvv * (nvv > 0 ? nvv - 1u : 0u));
      wsbf[OFF_LDIS] = (nvv > 1) ? (s / fmaxf(denom, 1.f)) : 0.f;
    }
    __syncthreads();
    if (sh_fall) return;
    unsigned myp = 0;
#pragma unroll
    for (int j = 0; j < 8; ++j) myp += wsb[OFF_H0 + tid * 8 + j];
    S[tid] = myp;
    __syncthreads();
#pragma unroll
    for (int off = 1; off < 256; off <<= 1) {
      unsigned v = (tid + off < 256) ? S[tid + off] : 0u;
      __syncthreads();
      S[tid] += v;
      __syncthreads();
    }
    {
      unsigned k = sh_k;
      unsigned suf = S[tid], sufn = suf - myp;
      if (suf >= k && sufn < k) {
        unsigned kk = k - sufn;
        unsigned cum2 = 0; int bin = tid * 8;
#pragma unroll
        for (int j = 7; j >= 0; --j) {
          unsigned h = wsb[OFF_H0 + tid * 8 + j]; cum2 += h;
          if (cum2 >= kk) { bin = tid * 8 + j; kk -= (cum2 - h); break; }
        }
        sh_pfx0 = (unsigned)bin;
        wsb[OFF_PFX0] = (unsigned)bin;   // dup same-value writes: benign
        wsb[OFF_K1] = kk;
      }
    }
    __syncthreads();
    const unsigned pfx = sh_pfx0;
    const unsigned kn = wsb[OFF_KN];
    for (int i = tid; i < 2048; i += 256) sh_h1[i] = 0u;
    __syncthreads();
    const unsigned* keys = ws + KEYS_BASE + (size_t)b * NPIX;
    for (unsigned i = bb * 256u + tid; i < kn; i += 16u * 256u) {
      unsigned key = keys[i];
      if ((key >> 21) == pfx) atomicAdd(&sh_h1[(key >> 10) & 0x7FFu], 1u);
    }
    __syncthreads();
    for (int i = tid; i < 2048; i += 256) {
      unsigned v = sh_h1[i]; if (v) atomicAdd(&wsb[OFF_H1 + i], v);
    }
  }
}

// ---- kCD: 16 blocks/batch. Redundant H1 scan -> pfx22,k2; then H2 hist -----
__global__ __launch_bounds__(256) void kCD(unsigned* __restrict__ ws) {
  const int b = blockIdx.y;
  unsigned* wsb = ws + (size_t)b * PER_BATCH;
  if (wsb[OFF_FALL]) return;
  __shared__ unsigned S[256];
  __shared__ unsigned sh_h2[1024];
  __shared__ unsigned sh_p22;
  const int tid = threadIdx.x;
  unsigned myp = 0;
#pragma unroll
  for (int j = 0; j < 8; ++j) myp += wsb[OFF_H1 + tid * 8 + j];
  S[tid] = myp;
  __syncthreads();
#pragma unroll
  for (int off = 1; off < 256; off <<= 1) {
    unsigned v = (tid + off < 256) ? S[tid + off] : 0u;
    __syncthreads();
    S[tid] += v;
    __syncthreads();
  }
  {
    unsigned k = wsb[OFF_K1];
    unsigned suf = S[tid], sufn = suf - myp;
    if (suf >= k && sufn < k) {
      unsigned kk = k - sufn;
      unsigned cum2 = 0; int bin = tid * 8;
#pragma unroll
      for (int j = 7; j >= 0; --j) {
        unsigned h = wsb[OFF_H1 + tid * 8 + j]; cum2 += h;
        if (cum2 >= kk) { bin = tid * 8 + j; kk -= (cum2 - h); break; }
      }
      unsigned p22 = (wsb[OFF_PFX0] << 11) | (unsigned)bin;
      sh_p22 = p22;
      wsb[OFF_PFX22] = p22;   // dup same-value writes: benign
      wsb[OFF_K2] = kk;
    }
  }
  __syncthreads();
  const unsigned pfx22 = sh_p22;
  const unsigned kn = wsb[OFF_KN];
  for (int i = tid; i < 1024; i += 256) sh_h2[i] = 0u;
  __syncthreads();
  const unsigned* keys = ws + KEYS_BASE + (size_t)b * NPIX;
  for (unsigned i = blockIdx.x * 256u + tid; i < kn; i += 16u * 256u) {
    unsigned key = keys[i];
    if ((key >> 10) == pfx22) atomicAdd(&sh_h2[key & 0x3FFu], 1u);
  }
  __syncthreads();
  for (int i = tid; i < 1024; i += 256) {
    unsigned v = sh_h2[i]; if (v) atomicAdd(&wsb[OFF_H2 + i], v);
  }
}

// ---- kEF: 16 blocks/batch. Redundant H2 scan -> thkey; then bt_neg ---------
__global__ __launch_bounds__(256) void kEF(unsigned* __restrict__ ws) {
  const int b = blockIdx.y;
  unsigned* wsb = ws + (size_t)b * PER_BATCH;
  float* wsbf = (float*)wsb;
  if (wsb[OFF_FALL]) return;
  __shared__ unsigned S[256];
  __shared__ unsigned sh_thk;
  __shared__ float sF[4];
  const int tid = threadIdx.x, lane = tid & 63, w = tid >> 6;
  unsigned myp = 0;
#pragma unroll
  for (int j = 0; j < 4; ++j) myp += wsb[OFF_H2 + tid * 4 + j];
  S[tid] = myp;
  __syncthreads();
#pragma unroll
  for (int off = 1; off < 256; off <<= 1) {
    unsigned v = (tid + off < 256) ? S[tid + off] : 0u;
    __syncthreads();
    S[tid] += v;
    __syncthreads();
  }
  {
    unsigned k = wsb[OFF_K2];
    unsigned suf = S[tid], sufn = suf - myp;
    if (suf >= k && sufn < k) {
      unsigned kk = k - sufn;
      unsigned cum2 = 0; int bin = tid * 4;
#pragma unroll
      for (int j = 3; j >= 0; --j) {
        unsigned h = wsb[OFF_H2 + tid * 4 + j]; cum2 += h;
        if (cum2 >= kk) { bin = tid * 4 + j; break; }
      }
      sh_thk = (wsb[OFF_PFX22] << 10) | (unsigned)bin;
    }
  }
  __syncthreads();
  const unsigned thkey = sh_thk;
  const unsigned knF = wsb[OFF_KNF];
  const unsigned* listB = ws + KEYS_BASE + (size_t)b * NPIX + (NPIX - knF);
  float part = 0.f;
  for (unsigned i = blockIdx.x * 256u + tid; i < knF; i += 16u * 256u) {
    unsigned key = listB[i];
    if (key >= thkey) {
      float sg = sigf(unmapf(key));
      part += sg * sg;
    }
  }
  part = wredf(part);
  if (lane == 0) sF[w] = part;
  __syncthreads();
  if (tid == 0) {
    float s = sF[0] + sF[1] + sF[2] + sF[3];
    if (s != 0.f) atomicAdd(&wsbf[OFF_BTN], s);
  }
}

// ---- kH: finalize 5 scalars -------------------------------------------------
__global__ void kH(const unsigned* __restrict__ ws, float* __restrict__ out) {
  __shared__ float sv[4][8];
  const int b = threadIdx.x;
  if (b < 8) {
    const unsigned* wsb = ws + (size_t)b * PER_BATCH;
    const float* wsbf = (const float*)wsb;
    int fall = (int)wsb[OFF_FALL];
    float at, bt, ct;
    if (fall) {
      at = wsbf[OFF_DICE + 3]; bt = wsbf[OFF_DICE + 4]; ct = wsbf[OFF_DICE + 5];
    } else {
      at = wsbf[OFF_DICE + 0];
      bt = wsbf[OFF_DICE + 1] + wsbf[OFF_BTN];
      ct = wsbf[OFF_DICE + 2];
    }
    float lt = 1.f - 2.f * at / ((bt + 1e-3f) + (ct + 1e-3f));
    float ak = wsbf[OFF_DICE + 6], bk = wsbf[OFF_DICE + 7] + 1e-3f, ck = wsbf[OFF_DICE + 8] + 1e-3f;
    float lk = 1.f - 2.f * ak / (bk + ck);
    unsigned vm = wsb[OFF_VM], nvv = wsb[OFF_NV];
    float s = 0.f;
    for (int k = 1; k < 8; ++k)
      if ((vm >> k) & 1) s += wsbf[OFF_AGG + k] / fmaxf((float)wsb[OFF_TC + k], 1.f);
    float la = s / fmaxf((float)nvv, 1.f);
    float ld = wsbf[OFF_LDIS];
    sv[0][b] = lt; sv[1][b] = lk; sv[2][b] = la; sv[3][b] = ld;
  }
  __syncthreads();
  if (threadIdx.x == 0) {
    float mt = 0.f, mk = 0.f, ma = 0.f, md = 0.f;
    for (int i = 0; i < 8; ++i) { mt += sv[0][i]; mk += sv[1][i]; ma += sv[2][i]; md += sv[3][i]; }
    mt *= 0.125f; mk *= 0.125f; ma *= 0.125f; md *= 0.125f;
    out[0] = mt + 0.5f * mk + 0.25f * (ma + md);
    out[1] = mt;
    out[2] = mk;
    out[3] = ma;
    out[4] = md;
  }
}

extern "C" void kernel_launch(void* const* d_in, const int* in_sizes, int n_in,
                              void* d_out, int out_size, void* d_ws, size_t ws_size,
                              hipStream_t stream) {
  const float* outputs = (const float*)d_in[0];
  const int* labels = (const int*)d_in[1];
  const float* tm = (const float*)d_in[2];
  unsigned* ws = (unsigned*)d_ws;
  float* out = (float*)d_out;

  dim3 blk(256);
  kZ<<<(HDR_WORDS + 255) / 256, blk, 0, stream>>>(ws);
  kXS<<<dim3(456, NB), blk, 0, stream>>>(outputs, labels, tm, ws);
  kGB<<<dim3(216, NB), blk, 0, stream>>>(outputs, labels, ws);
  kCD<<<dim3(16, NB), blk, 0, stream>>>(ws);
  kEF<<<dim3(16, NB), blk, 0, stream>>>(ws);
  kH<<<1, 64, 0, stream>>>(ws, out);
}